// Round 6
// baseline (843.192 us; speedup 1.0000x reference)
//
#include <hip/hip_runtime.h>
#include <math.h>

// ---- fixed problem sizes ----
#define NTOK 1024
#define DDIM 1024
#define HEADS 16
#define KVH 4
#define DH 64
#define BSZ 32
#define NSEL 8
#define WBLK 32            // NTOK / BSZ
#define GQ 4               // HEADS / KVH
#define CDIM 2048          // BSZ*DH
#define HIDN 2048
#define QKVD 1536          // (HEADS + 2*KVH)*DH
#define SCALE 0.125f       // DH^-0.5
#define NEGINF (-__builtin_inff())

typedef unsigned short u16;
typedef u16   u16x8  __attribute__((ext_vector_type(8)));
typedef short short8 __attribute__((ext_vector_type(8)));
typedef float f32x4  __attribute__((ext_vector_type(4)));

__device__ __forceinline__ u16 f2bf(float f) {
    unsigned u = __float_as_uint(f);
    return (u16)((u + 0x7fffu + ((u >> 16) & 1u)) >> 16);
}
__device__ __forceinline__ float bf2f(u16 h) { return __uint_as_float(((unsigned)h) << 16); }

__device__ __forceinline__ void glds16(const void* g, void* l) {
    __builtin_amdgcn_global_load_lds(
        (const __attribute__((address_space(1))) unsigned int*)g,
        (__attribute__((address_space(3))) unsigned int*)l, 16, 0, 0);
}

// element offset (in u16) of the 8-element lane-slot for (row, k..k+7) in the
// MFMA-fragment-tiled layout: 16-row x 32-k tiles, 1KB each, contiguous.
__device__ __forceinline__ size_t tiled_off(int row, int k, int K) {
    return ((size_t)((row >> 4) * (K >> 5) + (k >> 5)) * 64 +
            ((row & 15) | (((k >> 3) & 3) << 4))) * 8;
}

// ---------------------------------------------------------------------------
// K1: RMSNorm -> split-bf16 x in TILED layout (K=DDIM). 2 rows per 256-thr block.
// ---------------------------------------------------------------------------
__global__ void rmsnorm_kernel(const float* __restrict__ inp, const float* __restrict__ g,
                               u16* __restrict__ xhi, u16* __restrict__ xlo) {
    int t = threadIdx.x;
    int half = t >> 7, tid = t & 127;
    int n = blockIdx.x * 2 + half;
    const float4* row = (const float4*)(inp + (size_t)n * DDIM);
    float4 v0 = row[tid * 2], v1 = row[tid * 2 + 1];
    float ss = v0.x*v0.x + v0.y*v0.y + v0.z*v0.z + v0.w*v0.w
             + v1.x*v1.x + v1.y*v1.y + v1.z*v1.z + v1.w*v1.w;
    for (int off = 32; off; off >>= 1) ss += __shfl_down(ss, off);
    __shared__ float red[4];
    if ((t & 63) == 0) red[t >> 6] = ss;
    __syncthreads();
    float tot = red[half * 2] + red[half * 2 + 1];
    float r = 1.f / sqrtf(tot * (1.f / DDIM) + 1e-6f);
    const float4* gp = (const float4*)g;
    float4 g0 = gp[tid * 2], g1 = gp[tid * 2 + 1];
    float o[8] = { v0.x*r*g0.x, v0.y*r*g0.y, v0.z*r*g0.z, v0.w*r*g0.w,
                   v1.x*r*g1.x, v1.y*r*g1.y, v1.z*r*g1.z, v1.w*r*g1.w };
    u16x8 h, l;
#pragma unroll
    for (int i = 0; i < 8; ++i) {
        u16 hh = f2bf(o[i]);
        h[i] = hh;
        l[i] = f2bf(o[i] - bf2f(hh));
    }
    size_t ob = tiled_off(n, tid * 8, DDIM);
    *(u16x8*)&xhi[ob] = h;
    *(u16x8*)&xlo[ob] = l;
}

// ---------------------------------------------------------------------------
// K2: weight transpose + split: W[K][N] f32 -> tiled Bt[N][K] bf16 hi/lo
// ---------------------------------------------------------------------------
__global__ void transpose_split(const float* __restrict__ W, u16* __restrict__ Thi,
                                u16* __restrict__ Tlo, int K, int N) {
    __shared__ float tile[64][65];
    int k0 = blockIdx.y * 64, n0 = blockIdx.x * 64;
    int t = threadIdx.x;
    int r = t >> 4, c4 = (t & 15) * 4;
#pragma unroll
    for (int p = 0; p < 4; ++p) {
        float4 v = *(const float4*)&W[(size_t)(k0 + r + p * 16) * N + n0 + c4];
        tile[r + p * 16][c4 + 0] = v.x;
        tile[r + p * 16][c4 + 1] = v.y;
        tile[r + p * 16][c4 + 2] = v.z;
        tile[r + p * 16][c4 + 3] = v.w;
    }
    __syncthreads();
    int n = t >> 2, ks = (t & 3) * 16;
#pragma unroll
    for (int c = 0; c < 2; ++c) {
        u16x8 h, l;
#pragma unroll
        for (int j = 0; j < 8; ++j) {
            float v = tile[ks + c * 8 + j][n];
            u16 hh = f2bf(v);
            h[j] = hh;
            l[j] = f2bf(v - bf2f(hh));
        }
        size_t ob = tiled_off(n0 + n, k0 + ks + c * 8, K);
        *(u16x8*)&Thi[ob] = h;
        if (Tlo) *(u16x8*)&Tlo[ob] = l;
    }
}

// ---------------------------------------------------------------------------
// K2b: pad small weights [K][Xn] (Xn<=64) -> tiled split-bf16 [128][K] + padded bias
// ---------------------------------------------------------------------------
__global__ void pad_small_tiled(const float* __restrict__ W, const float* __restrict__ b,
                                u16* __restrict__ Thi, u16* __restrict__ Tlo,
                                float* __restrict__ bias_pad, int K, int Xn, int KLOG) {
    int idx = blockIdx.x * 256 + threadIdx.x;   // 128 * K/8
    int k = (idx & ((K >> 3) - 1)) * 8;
    int n = idx >> (KLOG - 3);
    if (n >= 128) return;
    u16x8 h, l;
#pragma unroll
    for (int j = 0; j < 8; ++j) {
        float v = (n < Xn) ? W[(size_t)(k + j) * Xn + n] : 0.f;
        u16 hh = f2bf(v);
        h[j] = hh;
        l[j] = f2bf(v - bf2f(hh));
    }
    size_t ob = tiled_off(n, k, K);
    *(u16x8*)&Thi[ob] = h;
    *(u16x8*)&Tlo[ob] = l;
    if (k == 0) bias_pad[n] = (n < Xn) ? b[n] : 0.f;
}

// ---------------------------------------------------------------------------
// K3: tiled MFMA GEMM with software pipeline + optional split-K.
// ---------------------------------------------------------------------------
template<int SPLIT, int ACT, int FINAL>
__global__ __launch_bounds__(256, 1)
void gemm_tiled(const u16* __restrict__ Ahi0, const u16* __restrict__ Alo0,
                const u16* __restrict__ Bhi0, const u16* __restrict__ Blo0,
                const float* __restrict__ bias0, float* __restrict__ C0,
                const u16* __restrict__ Ahi1, const u16* __restrict__ Alo1,
                const u16* __restrict__ Bhi1, const u16* __restrict__ Blo1,
                const float* __restrict__ bias1, float* __restrict__ C1,
                int M, int N, int K, int S) {
    int batch = blockIdx.z / S;
    int s = blockIdx.z - batch * S;
    const u16* Ahi = batch ? Ahi1 : Ahi0;
    const u16* Alo = batch ? Alo1 : Alo0;
    const u16* Bhi = batch ? Bhi1 : Bhi0;
    const u16* Blo = batch ? Blo1 : Blo0;
    const float* bias = batch ? bias1 : bias0;
    float* C = batch ? C1 : C0;

    constexpr int PARTS = (SPLIT == 3) ? 2 : 1;
    __shared__ u16 smA[2 * PARTS * 8 * 512];
    __shared__ u16 smB[2 * PARTS * 8 * 512];

    int tid = threadIdx.x;
    int w = tid >> 6, L = tid & 63;
    int m15 = L & 15, q = L >> 4;
    int KT = K >> 5;
    int rowTile = blockIdx.y * 8, colTile = blockIdx.x * 8;
    int NIT = (K / S) >> 5;
    int kb0 = s * NIT;
    int aw = w & 1, bw = w >> 1;

    f32x4 acc[4][4];
#pragma unroll
    for (int i = 0; i < 4; ++i)
#pragma unroll
        for (int j = 0; j < 4; ++j) acc[i][j] = (f32x4){0.f, 0.f, 0.f, 0.f};

    auto stage = [&](int buf, int kb) {
#pragma unroll
        for (int rl = 0; rl < 2; ++rl) {
            int rb = 2 * w + rl;
            glds16(Ahi + ((size_t)(rowTile + rb) * KT + kb) * 512 + (size_t)L * 8,
                   &smA[((buf * PARTS + 0) * 8 + rb) * 512]);
            glds16(Bhi + ((size_t)(colTile + rb) * KT + kb) * 512 + (size_t)L * 8,
                   &smB[((buf * PARTS + 0) * 8 + rb) * 512]);
            if constexpr (SPLIT == 3) {
                glds16(Alo + ((size_t)(rowTile + rb) * KT + kb) * 512 + (size_t)L * 8,
                       &smA[((buf * PARTS + 1) * 8 + rb) * 512]);
                glds16(Blo + ((size_t)(colTile + rb) * KT + kb) * 512 + (size_t)L * 8,
                       &smB[((buf * PARTS + 1) * 8 + rb) * 512]);
            }
        }
    };

    stage(0, kb0);
    for (int it = 0; it < NIT; ++it) {
        __syncthreads();
        if (it + 1 < NIT) stage((it + 1) & 1, kb0 + it + 1);
        int buf = it & 1;
        short8 ah[4], bh[4];
#pragma unroll
        for (int i = 0; i < 4; ++i) {
            ah[i] = *(const short8*)&smA[((buf * PARTS + 0) * 8 + aw * 4 + i) * 512 + L * 8];
            bh[i] = *(const short8*)&smB[((buf * PARTS + 0) * 8 + bw * 4 + i) * 512 + L * 8];
        }
        if constexpr (SPLIT == 3) {
            short8 al[4], bl[4];
#pragma unroll
            for (int i = 0; i < 4; ++i) {
                al[i] = *(const short8*)&smA[((buf * PARTS + 1) * 8 + aw * 4 + i) * 512 + L * 8];
                bl[i] = *(const short8*)&smB[((buf * PARTS + 1) * 8 + bw * 4 + i) * 512 + L * 8];
            }
#pragma unroll
            for (int i = 0; i < 4; ++i)
#pragma unroll
                for (int j = 0; j < 4; ++j) {
                    acc[i][j] = __builtin_amdgcn_mfma_f32_16x16x32_bf16(ah[i], bl[j], acc[i][j], 0, 0, 0);
                    acc[i][j] = __builtin_amdgcn_mfma_f32_16x16x32_bf16(al[i], bh[j], acc[i][j], 0, 0, 0);
                    acc[i][j] = __builtin_amdgcn_mfma_f32_16x16x32_bf16(ah[i], bh[j], acc[i][j], 0, 0, 0);
                }
        } else {
#pragma unroll
            for (int i = 0; i < 4; ++i)
#pragma unroll
                for (int j = 0; j < 4; ++j)
                    acc[i][j] = __builtin_amdgcn_mfma_f32_16x16x32_bf16(ah[i], bh[j], acc[i][j], 0, 0, 0);
        }
    }

    if constexpr (FINAL == 0) C += (size_t)s * M * N;
#pragma unroll
    for (int i = 0; i < 4; ++i) {
        int row = rowTile * 16 + aw * 64 + i * 16 + q * 4;
#pragma unroll
        for (int j = 0; j < 4; ++j) {
            int col = colTile * 16 + bw * 64 + j * 16 + m15;
            float bv = (FINAL && bias) ? bias[col] : 0.f;
#pragma unroll
            for (int r = 0; r < 4; ++r) {
                float v = acc[i][j][r];
                if constexpr (FINAL) {
                    v += bv;
                    if (ACT == 1) v = fmaxf(v, 0.f);
                    if (ACT == 2) v = 1.f / (1.f + expf(-v));
                }
                C[(size_t)(row + r) * N + col] = v;
            }
        }
    }
}

// ---------------------------------------------------------------------------
// K3b: split-K reduce -> f32 [M][N] with bias/act. Dual pointer sets via blockIdx.y.
// ---------------------------------------------------------------------------
template<int ACT>
__global__ void reduce_f32(const float* __restrict__ P0, const float* __restrict__ bias0,
                           float* __restrict__ C0,
                           const float* __restrict__ P1, const float* __restrict__ bias1,
                           float* __restrict__ C1, int S, int M, int N) {
    const float* P = blockIdx.y ? P1 : P0;
    const float* bias = blockIdx.y ? bias1 : bias0;
    float* C = blockIdx.y ? C1 : C0;
    int idx = blockIdx.x * 256 + threadIdx.x;
    int mn4 = (M * N) >> 2;
    if (idx >= mn4) return;
    f32x4 a = ((const f32x4*)P)[idx];
    for (int s = 1; s < S; ++s) a += ((const f32x4*)P)[(size_t)s * mn4 + idx];
    int col = (idx % (N >> 2)) * 4;
    f32x4 o;
#pragma unroll
    for (int j = 0; j < 4; ++j) {
        float v = a[j] + (bias ? bias[col + j] : 0.f);
        if (ACT == 1) v = fmaxf(v, 0.f);
        if (ACT == 2) v = 1.f / (1.f + expf(-v));
        o[j] = v;
    }
    ((f32x4*)C)[idx] = o;
}

// ---------------------------------------------------------------------------
// K3c: split-K reduce + relu + bias -> split-bf16 TILED (MLP1 hid, M=128, N=HIDN)
// ---------------------------------------------------------------------------
__global__ void reduce_hid(const float* __restrict__ P0, const float* __restrict__ b0,
                           u16* __restrict__ hi0, u16* __restrict__ lo0,
                           const float* __restrict__ P1, const float* __restrict__ b1,
                           u16* __restrict__ hi1, u16* __restrict__ lo1, int S) {
    const float* P = blockIdx.y ? P1 : P0;
    const float* bias = blockIdx.y ? b1 : b0;
    u16* hi = blockIdx.y ? hi1 : hi0;
    u16* lo = blockIdx.y ? lo1 : lo0;
    int idx = blockIdx.x * 256 + threadIdx.x;       // 128*2048/8 = 32768
    int col = (idx & 255) * 8, rowi = idx >> 8;
    size_t base = ((size_t)rowi * HIDN + col) >> 2;
    f32x4 a0 = ((const f32x4*)P)[base], a1 = ((const f32x4*)P)[base + 1];
    for (int s = 1; s < S; ++s) {
        size_t sb = (size_t)s * (128 * HIDN / 4) + base;
        a0 += ((const f32x4*)P)[sb];
        a1 += ((const f32x4*)P)[sb + 1];
    }
    u16x8 h, l;
#pragma unroll
    for (int j = 0; j < 8; ++j) {
        float v = (j < 4 ? a0[j] : a1[j - 4]) + bias[col + j];
        v = fmaxf(v, 0.f);
        u16 hh = f2bf(v);
        h[j] = hh;
        l[j] = f2bf(v - bf2f(hh));
    }
    size_t ob = tiled_off(rowi, col, HIDN);
    *(u16x8*)&hi[ob] = h;
    *(u16x8*)&lo[ob] = l;
}

// ---------------------------------------------------------------------------
// K3d: MLP2 split-K reduce + bias fused with mem_kv concat -> ck/cv [KVH][33][DH]
// ---------------------------------------------------------------------------
__global__ void reduce_ckcv(const float* __restrict__ Pk, const float* __restrict__ Pv,
                            const float* __restrict__ mem_kv,
                            const float* __restrict__ kb2, const float* __restrict__ vb2,
                            float* __restrict__ ck, float* __restrict__ cv, int S) {
    int idx = blockIdx.x * 256 + threadIdx.x;   // 4*33*64 = 8448
    if (idx >= KVH * 33 * DH) return;
    int d = idx & 63;
    int j = (idx >> 6) % 33;
    int h = idx / (33 * 64);
    float kvv, vvv;
    if (j == 0) {
        kvv = mem_kv[(0 * KVH + h) * DH + d];
        vvv = mem_kv[(1 * KVH + h) * DH + d];
    } else {
        size_t base = (size_t)(h * WBLK + (j - 1)) * 128 + d;
        float ak = Pk[base], av = Pv[base];
        for (int s = 1; s < S; ++s) {
            ak += Pk[(size_t)s * (128 * 128) + base];
            av += Pv[(size_t)s * (128 * 128) + base];
        }
        kvv = ak + kb2[d];
        vvv = av + vb2[d];
    }
    ck[idx] = kvv;
    cv[idx] = vvv;
}

// ---------------------------------------------------------------------------
// K5: build compress-MLP inputs -> split-bf16 TILED (K=CDIM)
// ---------------------------------------------------------------------------
__global__ void build_cmlp_in(const float* __restrict__ qkv, const float* __restrict__ k_pos,
                              const float* __restrict__ v_pos,
                              u16* __restrict__ ckhi, u16* __restrict__ cklo,
                              u16* __restrict__ cvhi, u16* __restrict__ cvlo) {
    int idx = blockIdx.x * 256 + threadIdx.x;   // 128 * 256 = 32768
    int k = (idx & 255) * 8;
    int r = idx >> 8;                           // 0..127 = h*W + w
    int p = k >> 6, d = k & 63;
    int h = r >> 5, wb = r & 31;
    int nn = wb * BSZ + p;
    const float* kq = qkv + (size_t)nn * QKVD + (HEADS + h) * DH + d;
    const float* vq = qkv + (size_t)nn * QKVD + (HEADS + KVH + h) * DH + d;
    const float* kp = k_pos + (size_t)(h * BSZ + p) * DH + d;
    const float* vp = v_pos + (size_t)(h * BSZ + p) * DH + d;
    u16x8 kh, kl, vh, vl;
#pragma unroll
    for (int j = 0; j < 8; ++j) {
        float kv = kq[j] + kp[j];
        float vv = vq[j] + vp[j];
        u16 a = f2bf(kv), b = f2bf(vv);
        kh[j] = a; kl[j] = f2bf(kv - bf2f(a));
        vh[j] = b; vl[j] = f2bf(vv - bf2f(b));
    }
    size_t ob = tiled_off(r, k, CDIM);
    *(u16x8*)&ckhi[ob] = kh; *(u16x8*)&cklo[ob] = kl;
    *(u16x8*)&cvhi[ob] = vh; *(u16x8*)&cvlo[ob] = vl;
}

// ---------------------------------------------------------------------------
// K7: interleaved rotary for q (16 heads), k (4 heads) + packed v copy (4 heads)
// ---------------------------------------------------------------------------
__global__ void rotary_kernel(const float* __restrict__ qkv,
                              float* __restrict__ qr, float* __restrict__ kr,
                              float* __restrict__ vr) {
    int idx = blockIdx.x * 256 + threadIdx.x;   // 24*1024*32 = 786432
    int i = idx & 31;
    int n = (idx >> 5) & 1023;
    int hd = idx >> 15;
    if (hd >= 24) return;
    if (hd >= HEADS + KVH) {       // packed v copy
        int h = hd - (HEADS + KVH);
        const float* src = qkv + (size_t)n * QKVD + (HEADS + KVH + h) * DH;
        float* dst = vr + ((size_t)h * NTOK + n) * DH;
        dst[2 * i] = src[2 * i];
        dst[2 * i + 1] = src[2 * i + 1];
        return;
    }
    float inv = powf(10000.f, -(float)i / 32.f);
    float fr = (float)n * inv;
    float c = cosf(fr), s = sinf(fr);
    const float* src; float* dst;
    if (hd < HEADS) { src = qkv + (size_t)n * QKVD + hd * DH;          dst = qr + ((size_t)hd * NTOK + n) * DH; }
    else { int h = hd - HEADS;
           src = qkv + (size_t)n * QKVD + (HEADS + h) * DH;            dst = kr + ((size_t)h * NTOK + n) * DH; }
    float x0 = src[2 * i], x1 = src[2 * i + 1];
    dst[2 * i]     = x0 * c - x1 * s;
    dst[2 * i + 1] = x1 * c + x0 * s;
}

// ---------------------------------------------------------------------------
// K8: compressed attention + importance + top-k. 4 tokens per 256-thr block.
// ---------------------------------------------------------------------------
__global__ __launch_bounds__(256)
void cattn_kernel(const float* __restrict__ qkv, const float* __restrict__ ck,
                  const float* __restrict__ cv, float* __restrict__ c_out,
                  int* __restrict__ sel, int* __restrict__ selmask) {
    int h = blockIdx.y;
    int tid = threadIdx.x;
    int w = tid >> 6, lane = tid & 63;
    int grp = lane >> 4, sub = lane & 15;
    int n = blockIdx.x * 4 + w;
    __shared__ float cks[33 * 68];
    __shared__ float cvs[33 * 68];
    __shared__ float sims[16 * 36];      // [w*4+g][j]

    for (int t4 = tid; t4 < 1056; t4 += 256) {
        int half = (t4 >= 528) ? 1 : 0;
        int u = t4 - half * 528;
        int j = u >> 4, d4 = (u & 15) * 4;
        const float* src = (half ? cv : ck) + (size_t)h * 33 * 64 + j * 64 + d4;
        float* dst = (half ? cvs : cks) + j * 68 + d4;
        *(float4*)dst = *(const float4*)src;
    }
    float qreg[64];
    {
        const float4* qp4 = (const float4*)(qkv + (size_t)n * QKVD + (h * GQ + grp) * DH);
#pragma unroll
        for (int c = 0; c < 16; ++c) {
            float4 v = qp4[c];
            qreg[4 * c] = v.x; qreg[4 * c + 1] = v.y; qreg[4 * c + 2] = v.z; qreg[4 * c + 3] = v.w;
        }
    }
    __syncthreads();

#pragma unroll
    for (int r = 0; r < 3; ++r) {
        int j = r * 16 + sub;
        if (j < 33) {
            float acc = 0.f;
#pragma unroll
            for (int d = 0; d < 64; ++d) acc = fmaf(qreg[d], cks[j * 68 + d], acc);
            sims[(w * 4 + grp) * 36 + j] = acc * SCALE;
        }
    }

    float ival = NEGINF;
    if (lane < 32)
        ival = 0.25f * (sims[(w * 4 + 0) * 36 + 1 + lane] + sims[(w * 4 + 1) * 36 + 1 + lane] +
                        sims[(w * 4 + 2) * 36 + 1 + lane] + sims[(w * 4 + 3) * 36 + 1 + lane]);
    float m = ival;
    for (int off = 32; off; off >>= 1) m = fmaxf(m, __shfl_xor(m, off));
    float e = (lane < 32) ? expf(ival - m) : 0.f;
    float sum = e;
    for (int off = 32; off; off >>= 1) sum += __shfl_xor(sum, off);
    float p = (lane < 32) ? e / sum : NEGINF;

    float v = p;
    int base = (h * NTOK + n) * 9;
    for (int t = 0; t < NSEL; ++t) {
        float bv = v; int bi = lane;
        for (int off = 32; off; off >>= 1) {
            float ov = __shfl_xor(bv, off);
            int   oi = __shfl_xor(bi, off);
            if (ov > bv || (ov == bv && oi < bi)) { bv = ov; bi = oi; }
        }
        if (lane == 0) { sel[base + t] = bi; selmask[base + t] = (bv > 1e-10f) ? 1 : 0; }
        if (lane == bi) v = NEGINF;
    }
    if (lane == 0) { sel[base + NSEL] = n >> 5; selmask[base + NSEL] = 1; }

#pragma unroll
    for (int g = 0; g < 4; ++g) {
        float sv = (lane < 33) ? sims[(w * 4 + g) * 36 + lane] : NEGINF;
        float mm = sv;
        for (int off = 32; off; off >>= 1) mm = fmaxf(mm, __shfl_xor(mm, off));
        float ee = (lane < 33) ? __expf(sv - mm) : 0.f;
        float ssum = ee;
        for (int off = 32; off; off >>= 1) ssum += __shfl_xor(ssum, off);
        if (lane < 33) sims[(w * 4 + g) * 36 + lane] = ee / ssum;
    }

    f32x4 o = (f32x4){0.f, 0.f, 0.f, 0.f};
#pragma unroll
    for (int j = 0; j < 33; ++j) {
        float a = sims[(w * 4 + grp) * 36 + j];
        f32x4 vv = *(const f32x4*)&cvs[j * 68 + sub * 4];
        o += a * vv;
    }
    *(f32x4*)&c_out[(((size_t)(h * GQ + grp)) * NTOK + n) * DH + sub * 4] = o;
}

// ---------------------------------------------------------------------------
// K9: fine attention v3 — wave w owns query head g=w end-to-end.
// Score: lane=jj (q in 64 VGPRs, Ks b128 conflict-free); online softmax
// lane-private (butterfly only); PV: lane=d, ps read via b128 broadcast.
// Register prefetch pipeline: global->VGPR for pair bp+1 overlaps compute(bp).
// 11 barriers total (vs 20 in v2).
// ---------------------------------------------------------------------------
__global__ __launch_bounds__(256)
void fattn_kernel(const float* __restrict__ qr, const float* __restrict__ kr,
                  const float* __restrict__ vr, const int* __restrict__ sel,
                  const int* __restrict__ selmask, float* __restrict__ f_out) {
    int n = blockIdx.x, h = blockIdx.y;
    int tid = threadIdx.x;
    int w = tid >> 6, lane = tid & 63;
    __shared__ float Ks[64 * 68];
    __shared__ float Vs[64 * 68];
    __shared__ float ps[4 * 68];
    __shared__ int sel_s[9], msk_s[9];

    if (tid < 9) {
        sel_s[tid] = sel[(h * NTOK + n) * 9 + tid];
        msk_s[tid] = selmask[(h * NTOK + n) * 9 + tid];
    }
    float qreg[64];
    {
        const float4* qp4 = (const float4*)(qr + (((size_t)(h * GQ + w)) * NTOK + n) * DH);
#pragma unroll
        for (int c = 0; c < 16; ++c) {
            float4 vv = qp4[c];
            qreg[4 * c] = vv.x; qreg[4 * c + 1] = vv.y; qreg[4 * c + 2] = vv.z; qreg[4 * c + 3] = vv.w;
        }
    }
    float o = 0.f;
    float m_run = -3.402823466e38f, l_run = 0.f;
    __syncthreads();   // sel_s ready

    // prefetch registers: 4 (row,d4) tasks per thread, K + V
    float4 pk[4], pv[4];
    int rowt = (tid >> 4);            // base row for i=0 (rows 0..15), +16 per i
    int d4 = (tid & 15) * 4;

    auto prefetch = [&](int bp) {
#pragma unroll
        for (int i = 0; i < 4; ++i) {
            int row = rowt + i * 16;
            int s9 = bp * 2 + (row >> 5);
            if (s9 > 8) s9 = 8;       // bp=4 rows 32..63: harmless duplicate (masked)
            int blk = sel_s[s9];
            size_t gb = ((size_t)h * NTOK + blk * BSZ + (row & 31)) * DH + d4;
            pk[i] = *(const float4*)&kr[gb];
            pv[i] = *(const float4*)&vr[gb];
        }
    };

    prefetch(0);
    for (int bp = 0; bp < 5; ++bp) {
        // store prefetched pair into LDS
#pragma unroll
        for (int i = 0; i < 4; ++i) {
            int row = rowt + i * 16;
            *(float4*)&Ks[row * 68 + d4] = pk[i];
            *(float4*)&Vs[row * 68 + d4] = pv[i];
        }
        __syncthreads();
        if (bp < 4) prefetch(bp + 1);

        // score: lane = jj
        int b9 = bp * 2 + (lane >> 5);
        bool valid = (b9 < 9) && msk_s[b9];
        float s = -3.402823466e38f;
        if (valid) {
            float acc = 0.f;
#pragma unroll
            for (int c = 0; c < 16; ++c) {
                f32x4 k4 = *(const f32x4*)&Ks[lane * 68 + c * 4];
                acc = fmaf(qreg[4 * c + 0], k4[0], acc);
                acc = fmaf(qreg[4 * c + 1], k4[1], acc);
                acc = fmaf(qreg[4 * c + 2], k4[2], acc);
                acc = fmaf(qreg[4 * c + 3], k4[3], acc);
            }
            s = acc * SCALE;
        }
        // online softmax, lane-private
        float mb = s;
        for (int off = 32; off; off >>= 1) mb = fmaxf(mb, __shfl_xor(mb, off));
        float m_new = fmaxf(m_run, mb);
        float pp = valid ? __expf(s - m_new) : 0.f;
        float alpha = __expf(m_run - m_new);
        float psum = pp;
        for (int off = 32; off; off >>= 1) psum += __shfl_xor(psum, off);
        l_run = l_run * alpha + psum;
        m_run = m_new;
        ps[w * 68 + lane] = pp;

        // PV: lane = d
        o *= alpha;
#pragma unroll
        for (int j4 = 0; j4 < 16; ++j4) {
            f32x4 p4 = *(const f32x4*)&ps[w * 68 + j4 * 4];
            o = fmaf(p4[0], Vs[(j4 * 4 + 0) * 68 + lane], o);
            o = fmaf(p4[1], Vs[(j4 * 4 + 1) * 68 + lane], o);
            o = fmaf(p4[2], Vs[(j4 * 4 + 2) * 68 + lane], o);
            o = fmaf(p4[3], Vs[(j4 * 4 + 3) * 68 + lane], o);
        }
        __syncthreads();
    }
    f_out[(((size_t)(h * GQ + w)) * NTOK + n) * DH + lane] = o / l_run;
}

// ---------------------------------------------------------------------------
// K10: gated mix -> split-bf16 TILED (K=DDIM). gates f32 [N][128] padded.
// ---------------------------------------------------------------------------
__global__ void mix_kernel(const float* __restrict__ gates, const float* __restrict__ c_out,
                           const float* __restrict__ f_out,
                           u16* __restrict__ mixhi, u16* __restrict__ mixlo) {
    int idx = blockIdx.x * 256 + threadIdx.x;   // 1024*1024/8 = 131072
    int col = (idx & 127) * 8;
    int n = idx >> 7;
    int hd = col >> 6, d = col & 63;
    float g0 = gates[(size_t)n * 128 + hd * 2];
    float g1 = gates[(size_t)n * 128 + hd * 2 + 1];
    size_t hoff = (((size_t)hd) * NTOK + n) * DH + d;
    u16x8 h, l;
#pragma unroll
    for (int j = 0; j < 8; ++j) {
        float v = g0 * c_out[hoff + j] + g1 * f_out[hoff + j];
        u16 hh = f2bf(v);
        h[j] = hh;
        l[j] = f2bf(v - bf2f(hh));
    }
    size_t ob = tiled_off(n, col, DDIM);
    *(u16x8*)&mixhi[ob] = h;
    *(u16x8*)&mixlo[ob] = l;
}

// ---------------------------------------------------------------------------
extern "C" void kernel_launch(void* const* d_in, const int* in_sizes, int n_in,
                              void* d_out, int out_size, void* d_ws, size_t ws_size,
                              hipStream_t stream) {
    const float* inp    = (const float*)d_in[0];
    const float* g_norm = (const float*)d_in[1];
    const float* w_qkv  = (const float*)d_in[2];
    const float* mem_kv = (const float*)d_in[3];
    const float* k_pos  = (const float*)d_in[4];
    const float* v_pos  = (const float*)d_in[5];
    const float* k_w1   = (const float*)d_in[6];
    const float* k_b1   = (const float*)d_in[7];
    const float* k_w2   = (const float*)d_in[8];
    const float* k_b2   = (const float*)d_in[9];
    const float* v_w1   = (const float*)d_in[10];
    const float* v_b1   = (const float*)d_in[11];
    const float* v_w2   = (const float*)d_in[12];
    const float* v_b2   = (const float*)d_in[13];
    const float* gate_w = (const float*)d_in[14];
    const float* gate_b = (const float*)d_in[15];
    const float* w_out  = (const float*)d_in[16];
    float* out = (float*)d_out;

    char* wsb = (char*)d_ws;
    size_t off = 0;
    auto alloc = [&](size_t bytes) -> void* {
        void* p = wsb + off;
        off = (off + bytes + 255) & ~(size_t)255;
        return p;
    };
    u16*   xhi    = (u16*)  alloc((size_t)NTOK * DDIM * 2);
    u16*   xlo    = (u16*)  alloc((size_t)NTOK * DDIM * 2);
    float* qkvb   = (float*)alloc((size_t)NTOK * QKVD * 4);
    u16*   wqThi  = (u16*)  alloc((size_t)QKVD * DDIM * 2);
    u16*   wqTlo  = (u16*)  alloc((size_t)QKVD * DDIM * 2);
    u16*   kw1Thi = (u16*)  alloc((size_t)HIDN * CDIM * 2);
    u16*   kw1Tlo = (u16*)  alloc((size_t)HIDN * CDIM * 2);
    u16*   vw1Thi = (u16*)  alloc((size_t)HIDN * CDIM * 2);
    u16*   vw1Tlo = (u16*)  alloc((size_t)HIDN * CDIM * 2);
    u16*   woThi  = (u16*)  alloc((size_t)DDIM * DDIM * 2);
    u16*   gwThi  = (u16*)  alloc((size_t)128 * DDIM * 2);
    u16*   gwTlo  = (u16*)  alloc((size_t)128 * DDIM * 2);
    float* gbp    = (float*)alloc(128 * 4);
    u16*   kw2Thi = (u16*)  alloc((size_t)128 * HIDN * 2);
    u16*   kw2Tlo = (u16*)  alloc((size_t)128 * HIDN * 2);
    float* kb2p   = (float*)alloc(128 * 4);
    u16*   vw2Thi = (u16*)  alloc((size_t)128 * HIDN * 2);
    u16*   vw2Tlo = (u16*)  alloc((size_t)128 * HIDN * 2);
    float* vb2p   = (float*)alloc(128 * 4);
    u16*   cinkhi = (u16*)  alloc((size_t)128 * CDIM * 2);
    u16*   cinklo = (u16*)  alloc((size_t)128 * CDIM * 2);
    u16*   cinvhi = (u16*)  alloc((size_t)128 * CDIM * 2);
    u16*   cinvlo = (u16*)  alloc((size_t)128 * CDIM * 2);
    u16*   hidkhi = (u16*)  alloc((size_t)128 * HIDN * 2);
    u16*   hidklo = (u16*)  alloc((size_t)128 * HIDN * 2);
    u16*   hidvhi = (u16*)  alloc((size_t)128 * HIDN * 2);
    u16*   hidvlo = (u16*)  alloc((size_t)128 * HIDN * 2);
    float* Pg     = (float*)alloc((size_t)8 * NTOK * 128 * 4);
    float* Pm1k   = (float*)alloc((size_t)4 * 128 * HIDN * 4);
    float* Pm1v   = (float*)alloc((size_t)4 * 128 * HIDN * 4);
    float* Pm2k   = (float*)alloc((size_t)8 * 128 * 128 * 4);
    float* Pm2v   = (float*)alloc((size_t)8 * 128 * 128 * 4);
    float* ck     = (float*)alloc((size_t)KVH * 33 * DH * 4);
    float* cv     = (float*)alloc((size_t)KVH * 33 * DH * 4);
    float* qr     = (float*)alloc((size_t)HEADS * NTOK * DH * 4);
    float* kr     = (float*)alloc((size_t)KVH * NTOK * DH * 4);
    float* vr     = (float*)alloc((size_t)KVH * NTOK * DH * 4);
    float* c_out  = (float*)alloc((size_t)HEADS * NTOK * DH * 4);
    float* f_out  = (float*)alloc((size_t)HEADS * NTOK * DH * 4);
    float* gates  = (float*)alloc((size_t)NTOK * 128 * 4);
    int*   sel    = (int*)  alloc((size_t)KVH * NTOK * 9 * 4);
    int*   selmask= (int*)  alloc((size_t)KVH * NTOK * 9 * 4);
    u16*   mixhi  = (u16*)  alloc((size_t)NTOK * DDIM * 2);
    u16*   mixlo  = (u16*)  alloc((size_t)NTOK * DDIM * 2);

    // weight prep (tiled layouts)
    transpose_split<<<dim3(QKVD / 64, DDIM / 64), 256, 0, stream>>>(w_qkv, wqThi, wqTlo, DDIM, QKVD);
    transpose_split<<<dim3(HIDN / 64, CDIM / 64), 256, 0, stream>>>(k_w1, kw1Thi, kw1Tlo, CDIM, HIDN);
    transpose_split<<<dim3(HIDN / 64, CDIM / 64), 256, 0, stream>>>(v_w1, vw1Thi, vw1Tlo, CDIM, HIDN);
    transpose_split<<<dim3(DDIM / 64, DDIM / 64), 256, 0, stream>>>(w_out, woThi, nullptr, DDIM, DDIM);
    pad_small_tiled<<<(128 * DDIM / 8) / 256, 256, 0, stream>>>(gate_w, gate_b, gwThi, gwTlo, gbp, DDIM, 32, 10);
    pad_small_tiled<<<(128 * HIDN / 8) / 256, 256, 0, stream>>>(k_w2, k_b2, kw2Thi, kw2Tlo, kb2p, HIDN, 64, 11);
    pad_small_tiled<<<(128 * HIDN / 8) / 256, 256, 0, stream>>>(v_w2, v_b2, vw2Thi, vw2Tlo, vb2p, HIDN, 64, 11);

    // 1. RMSNorm -> tiled split-bf16 x
    rmsnorm_kernel<<<NTOK / 2, 256, 0, stream>>>(inp, g_norm, xhi, xlo);
    // 2. qkv = x @ w_qkv (final f32)
    gemm_tiled<3, 0, 1><<<dim3(QKVD / 128, NTOK / 128, 1), 256, 0, stream>>>(
        xhi, xlo, wqThi, wqTlo, nullptr, qkvb,
        xhi, xlo, wqThi, wqTlo, nullptr, qkvb, NTOK, QKVD, DDIM, 1);
    // 3. gates (split-K 8 + sigmoid reduce)
    gemm_tiled<3, 0, 0><<<dim3(1, NTOK / 128, 8), 256, 0, stream>>>(
        xhi, xlo, gwThi, gwTlo, nullptr, Pg,
        xhi, xlo, gwThi, gwTlo, nullptr, Pg, NTOK, 128, DDIM, 8);
    reduce_f32<2><<<dim3(128, 1), 256, 0, stream>>>(Pg, gbp, gates, Pg, gbp, gates, 8, NTOK, 128);
    // 4. compress-MLP inputs (tiled)
    build_cmlp_in<<<128, 256, 0, stream>>>(qkvb, k_pos, v_pos, cinkhi, cinklo, cinvhi, cinvlo);
    // 5. MLP1 (split-K 4, k&v batched; relu+bias+split-tile in reduce)
    gemm_tiled<3, 0, 0><<<dim3(HIDN / 128, 1, 8), 256, 0, stream>>>(
        cinkhi, cinklo, kw1Thi, kw1Tlo, nullptr, Pm1k,
        cinvhi, cinvlo, vw1Thi, vw1Tlo, nullptr, Pm1v, 128, HIDN, CDIM, 4);
    reduce_hid<<<dim3(128, 2), 256, 0, stream>>>(Pm1k, k_b1, hidkhi, hidklo,
                                                 Pm1v, v_b1, hidvhi, hidvlo, 4);
    // 6. MLP2 (split-K 8, k&v batched) + fused reduce/bias/concat
    gemm_tiled<3, 0, 0><<<dim3(1, 1, 16), 256, 0, stream>>>(
        hidkhi, hidklo, kw2Thi, kw2Tlo, nullptr, Pm2k,
        hidvhi, hidvlo, vw2Thi, vw2Tlo, nullptr, Pm2v, 128, 128, HIDN, 8);
    reduce_ckcv<<<33, 256, 0, stream>>>(Pm2k, Pm2v, mem_kv, kb2p, vb2p, ck, cv, 8);
    // 8. rotary + packed v
    rotary_kernel<<<(24 * NTOK * 32) / 256, 256, 0, stream>>>(qkvb, qr, kr, vr);
    // 9. compressed attention + selection (4 tokens per block)
    cattn_kernel<<<dim3(NTOK / 4, KVH), 256, 0, stream>>>(qkvb, ck, cv, c_out, sel, selmask);
    // 10. fine attention (wave-per-head online softmax, reg-prefetch pipeline)
    fattn_kernel<<<dim3(NTOK, KVH), 256, 0, stream>>>(qr, kr, vr, sel, selmask, f_out);
    // 11. gated mix -> tiled split-bf16
    mix_kernel<<<(NTOK * DDIM / 8) / 256, 256, 0, stream>>>(gates, c_out, f_out, mixhi, mixlo);
    // 12. output projection (bf16, final)
    gemm_tiled<1, 0, 1><<<dim3(DDIM / 128, NTOK / 128, 1), 256, 0, stream>>>(
        mixhi, mixhi, woThi, woThi, nullptr, out,
        mixhi, mixhi, woThi, woThi, nullptr, out, NTOK, DDIM, DDIM, 1);
}

// Round 7
// 570.271 us; speedup vs baseline: 1.4786x; 1.4786x over previous
//
#include <hip/hip_runtime.h>
#include <math.h>

// ---- fixed problem sizes ----
#define NTOK 1024
#define DDIM 1024
#define HEADS 16
#define KVH 4
#define DH 64
#define BSZ 32
#define NSEL 8
#define WBLK 32            // NTOK / BSZ
#define GQ 4               // HEADS / KVH
#define CDIM 2048          // BSZ*DH
#define HIDN 2048
#define QKVD 1536          // (HEADS + 2*KVH)*DH
#define SCALE 0.125f       // DH^-0.5
#define NEGINF (-__builtin_inff())

typedef unsigned short u16;
typedef u16   u16x8  __attribute__((ext_vector_type(8)));
typedef short short8 __attribute__((ext_vector_type(8)));
typedef float f32x4  __attribute__((ext_vector_type(4)));

__device__ __forceinline__ u16 f2bf(float f) {
    unsigned u = __float_as_uint(f);
    return (u16)((u + 0x7fffu + ((u >> 16) & 1u)) >> 16);
}
__device__ __forceinline__ float bf2f(u16 h) { return __uint_as_float(((unsigned)h) << 16); }

__device__ __forceinline__ void glds16(const void* g, void* l) {
    __builtin_amdgcn_global_load_lds(
        (const __attribute__((address_space(1))) unsigned int*)g,
        (__attribute__((address_space(3))) unsigned int*)l, 16, 0, 0);
}

// element offset (in u16) of the 8-element lane-slot for (row, k..k+7) in the
// MFMA-fragment-tiled layout: 16-row x 32-k tiles, 1KB each, contiguous.
__device__ __forceinline__ size_t tiled_off(int row, int k, int K) {
    return ((size_t)((row >> 4) * (K >> 5) + (k >> 5)) * 64 +
            ((row & 15) | (((k >> 3) & 3) << 4))) * 8;
}

// ---------------------------------------------------------------------------
// K1: RMSNorm -> split-bf16 x in TILED layout (K=DDIM). 2 rows per 256-thr block.
// ---------------------------------------------------------------------------
__global__ void rmsnorm_kernel(const float* __restrict__ inp, const float* __restrict__ g,
                               u16* __restrict__ xhi, u16* __restrict__ xlo) {
    int t = threadIdx.x;
    int half = t >> 7, tid = t & 127;
    int n = blockIdx.x * 2 + half;
    const float4* row = (const float4*)(inp + (size_t)n * DDIM);
    float4 v0 = row[tid * 2], v1 = row[tid * 2 + 1];
    float ss = v0.x*v0.x + v0.y*v0.y + v0.z*v0.z + v0.w*v0.w
             + v1.x*v1.x + v1.y*v1.y + v1.z*v1.z + v1.w*v1.w;
    for (int off = 32; off; off >>= 1) ss += __shfl_down(ss, off);
    __shared__ float red[4];
    if ((t & 63) == 0) red[t >> 6] = ss;
    __syncthreads();
    float tot = red[half * 2] + red[half * 2 + 1];
    float r = 1.f / sqrtf(tot * (1.f / DDIM) + 1e-6f);
    const float4* gp = (const float4*)g;
    float4 g0 = gp[tid * 2], g1 = gp[tid * 2 + 1];
    float o[8] = { v0.x*r*g0.x, v0.y*r*g0.y, v0.z*r*g0.z, v0.w*r*g0.w,
                   v1.x*r*g1.x, v1.y*r*g1.y, v1.z*r*g1.z, v1.w*r*g1.w };
    u16x8 h, l;
#pragma unroll
    for (int i = 0; i < 8; ++i) {
        u16 hh = f2bf(o[i]);
        h[i] = hh;
        l[i] = f2bf(o[i] - bf2f(hh));
    }
    size_t ob = tiled_off(n, tid * 8, DDIM);
    *(u16x8*)&xhi[ob] = h;
    *(u16x8*)&xlo[ob] = l;
}

// ---------------------------------------------------------------------------
// K2: weight transpose + split: W[K][N] f32 -> tiled Bt[N][K] bf16 hi/lo
// ---------------------------------------------------------------------------
__global__ void transpose_split(const float* __restrict__ W, u16* __restrict__ Thi,
                                u16* __restrict__ Tlo, int K, int N) {
    __shared__ float tile[64][65];
    int k0 = blockIdx.y * 64, n0 = blockIdx.x * 64;
    int t = threadIdx.x;
    int r = t >> 4, c4 = (t & 15) * 4;
#pragma unroll
    for (int p = 0; p < 4; ++p) {
        float4 v = *(const float4*)&W[(size_t)(k0 + r + p * 16) * N + n0 + c4];
        tile[r + p * 16][c4 + 0] = v.x;
        tile[r + p * 16][c4 + 1] = v.y;
        tile[r + p * 16][c4 + 2] = v.z;
        tile[r + p * 16][c4 + 3] = v.w;
    }
    __syncthreads();
    int n = t >> 2, ks = (t & 3) * 16;
#pragma unroll
    for (int c = 0; c < 2; ++c) {
        u16x8 h, l;
#pragma unroll
        for (int j = 0; j < 8; ++j) {
            float v = tile[ks + c * 8 + j][n];
            u16 hh = f2bf(v);
            h[j] = hh;
            l[j] = f2bf(v - bf2f(hh));
        }
        size_t ob = tiled_off(n0 + n, k0 + ks + c * 8, K);
        *(u16x8*)&Thi[ob] = h;
        if (Tlo) *(u16x8*)&Tlo[ob] = l;
    }
}

// ---------------------------------------------------------------------------
// K2b: pad small weights [K][Xn] (Xn<=64) -> tiled split-bf16 [128][K] + padded bias
// ---------------------------------------------------------------------------
__global__ void pad_small_tiled(const float* __restrict__ W, const float* __restrict__ b,
                                u16* __restrict__ Thi, u16* __restrict__ Tlo,
                                float* __restrict__ bias_pad, int K, int Xn, int KLOG) {
    int idx = blockIdx.x * 256 + threadIdx.x;   // 128 * K/8
    int k = (idx & ((K >> 3) - 1)) * 8;
    int n = idx >> (KLOG - 3);
    if (n >= 128) return;
    u16x8 h, l;
#pragma unroll
    for (int j = 0; j < 8; ++j) {
        float v = (n < Xn) ? W[(size_t)(k + j) * Xn + n] : 0.f;
        u16 hh = f2bf(v);
        h[j] = hh;
        l[j] = f2bf(v - bf2f(hh));
    }
    size_t ob = tiled_off(n, k, K);
    *(u16x8*)&Thi[ob] = h;
    *(u16x8*)&Tlo[ob] = l;
    if (k == 0) bias_pad[n] = (n < Xn) ? b[n] : 0.f;
}

// ---------------------------------------------------------------------------
// K3: tiled MFMA GEMM with software pipeline + optional split-K.
// ---------------------------------------------------------------------------
template<int SPLIT, int ACT, int FINAL>
__global__ __launch_bounds__(256, 1)
void gemm_tiled(const u16* __restrict__ Ahi0, const u16* __restrict__ Alo0,
                const u16* __restrict__ Bhi0, const u16* __restrict__ Blo0,
                const float* __restrict__ bias0, float* __restrict__ C0,
                const u16* __restrict__ Ahi1, const u16* __restrict__ Alo1,
                const u16* __restrict__ Bhi1, const u16* __restrict__ Blo1,
                const float* __restrict__ bias1, float* __restrict__ C1,
                int M, int N, int K, int S) {
    int batch = blockIdx.z / S;
    int s = blockIdx.z - batch * S;
    const u16* Ahi = batch ? Ahi1 : Ahi0;
    const u16* Alo = batch ? Alo1 : Alo0;
    const u16* Bhi = batch ? Bhi1 : Bhi0;
    const u16* Blo = batch ? Blo1 : Blo0;
    const float* bias = batch ? bias1 : bias0;
    float* C = batch ? C1 : C0;

    constexpr int PARTS = (SPLIT == 3) ? 2 : 1;
    __shared__ u16 smA[2 * PARTS * 8 * 512];
    __shared__ u16 smB[2 * PARTS * 8 * 512];

    int tid = threadIdx.x;
    int w = tid >> 6, L = tid & 63;
    int m15 = L & 15, q = L >> 4;
    int KT = K >> 5;
    int rowTile = blockIdx.y * 8, colTile = blockIdx.x * 8;
    int NIT = (K / S) >> 5;
    int kb0 = s * NIT;
    int aw = w & 1, bw = w >> 1;

    f32x4 acc[4][4];
#pragma unroll
    for (int i = 0; i < 4; ++i)
#pragma unroll
        for (int j = 0; j < 4; ++j) acc[i][j] = (f32x4){0.f, 0.f, 0.f, 0.f};

    auto stage = [&](int buf, int kb) {
#pragma unroll
        for (int rl = 0; rl < 2; ++rl) {
            int rb = 2 * w + rl;
            glds16(Ahi + ((size_t)(rowTile + rb) * KT + kb) * 512 + (size_t)L * 8,
                   &smA[((buf * PARTS + 0) * 8 + rb) * 512]);
            glds16(Bhi + ((size_t)(colTile + rb) * KT + kb) * 512 + (size_t)L * 8,
                   &smB[((buf * PARTS + 0) * 8 + rb) * 512]);
            if constexpr (SPLIT == 3) {
                glds16(Alo + ((size_t)(rowTile + rb) * KT + kb) * 512 + (size_t)L * 8,
                       &smA[((buf * PARTS + 1) * 8 + rb) * 512]);
                glds16(Blo + ((size_t)(colTile + rb) * KT + kb) * 512 + (size_t)L * 8,
                       &smB[((buf * PARTS + 1) * 8 + rb) * 512]);
            }
        }
    };

    stage(0, kb0);
    for (int it = 0; it < NIT; ++it) {
        __syncthreads();
        if (it + 1 < NIT) stage((it + 1) & 1, kb0 + it + 1);
        int buf = it & 1;
        short8 ah[4], bh[4];
#pragma unroll
        for (int i = 0; i < 4; ++i) {
            ah[i] = *(const short8*)&smA[((buf * PARTS + 0) * 8 + aw * 4 + i) * 512 + L * 8];
            bh[i] = *(const short8*)&smB[((buf * PARTS + 0) * 8 + bw * 4 + i) * 512 + L * 8];
        }
        if constexpr (SPLIT == 3) {
            short8 al[4], bl[4];
#pragma unroll
            for (int i = 0; i < 4; ++i) {
                al[i] = *(const short8*)&smA[((buf * PARTS + 1) * 8 + aw * 4 + i) * 512 + L * 8];
                bl[i] = *(const short8*)&smB[((buf * PARTS + 1) * 8 + bw * 4 + i) * 512 + L * 8];
            }
#pragma unroll
            for (int i = 0; i < 4; ++i)
#pragma unroll
                for (int j = 0; j < 4; ++j) {
                    acc[i][j] = __builtin_amdgcn_mfma_f32_16x16x32_bf16(ah[i], bl[j], acc[i][j], 0, 0, 0);
                    acc[i][j] = __builtin_amdgcn_mfma_f32_16x16x32_bf16(al[i], bh[j], acc[i][j], 0, 0, 0);
                    acc[i][j] = __builtin_amdgcn_mfma_f32_16x16x32_bf16(ah[i], bh[j], acc[i][j], 0, 0, 0);
                }
        } else {
#pragma unroll
            for (int i = 0; i < 4; ++i)
#pragma unroll
                for (int j = 0; j < 4; ++j)
                    acc[i][j] = __builtin_amdgcn_mfma_f32_16x16x32_bf16(ah[i], bh[j], acc[i][j], 0, 0, 0);
        }
    }

    if constexpr (FINAL == 0) C += (size_t)s * M * N;
#pragma unroll
    for (int i = 0; i < 4; ++i) {
        int row = rowTile * 16 + aw * 64 + i * 16 + q * 4;
#pragma unroll
        for (int j = 0; j < 4; ++j) {
            int col = colTile * 16 + bw * 64 + j * 16 + m15;
            float bv = (FINAL && bias) ? bias[col] : 0.f;
#pragma unroll
            for (int r = 0; r < 4; ++r) {
                float v = acc[i][j][r];
                if constexpr (FINAL) {
                    v += bv;
                    if (ACT == 1) v = fmaxf(v, 0.f);
                    if (ACT == 2) v = 1.f / (1.f + expf(-v));
                }
                C[(size_t)(row + r) * N + col] = v;
            }
        }
    }
}

// ---------------------------------------------------------------------------
// K3b: split-K reduce -> f32 [M][N] with bias/act. Dual pointer sets via blockIdx.y.
// ---------------------------------------------------------------------------
template<int ACT>
__global__ void reduce_f32(const float* __restrict__ P0, const float* __restrict__ bias0,
                           float* __restrict__ C0,
                           const float* __restrict__ P1, const float* __restrict__ bias1,
                           float* __restrict__ C1, int S, int M, int N) {
    const float* P = blockIdx.y ? P1 : P0;
    const float* bias = blockIdx.y ? bias1 : bias0;
    float* C = blockIdx.y ? C1 : C0;
    int idx = blockIdx.x * 256 + threadIdx.x;
    int mn4 = (M * N) >> 2;
    if (idx >= mn4) return;
    f32x4 a = ((const f32x4*)P)[idx];
    for (int s = 1; s < S; ++s) a += ((const f32x4*)P)[(size_t)s * mn4 + idx];
    int col = (idx % (N >> 2)) * 4;
    f32x4 o;
#pragma unroll
    for (int j = 0; j < 4; ++j) {
        float v = a[j] + (bias ? bias[col + j] : 0.f);
        if (ACT == 1) v = fmaxf(v, 0.f);
        if (ACT == 2) v = 1.f / (1.f + expf(-v));
        o[j] = v;
    }
    ((f32x4*)C)[idx] = o;
}

// ---------------------------------------------------------------------------
// K3c: split-K reduce + relu + bias -> split-bf16 TILED (MLP1 hid, M=128, N=HIDN)
// ---------------------------------------------------------------------------
__global__ void reduce_hid(const float* __restrict__ P0, const float* __restrict__ b0,
                           u16* __restrict__ hi0, u16* __restrict__ lo0,
                           const float* __restrict__ P1, const float* __restrict__ b1,
                           u16* __restrict__ hi1, u16* __restrict__ lo1, int S) {
    const float* P = blockIdx.y ? P1 : P0;
    const float* bias = blockIdx.y ? b1 : b0;
    u16* hi = blockIdx.y ? hi1 : hi0;
    u16* lo = blockIdx.y ? lo1 : lo0;
    int idx = blockIdx.x * 256 + threadIdx.x;       // 128*2048/8 = 32768
    int col = (idx & 255) * 8, rowi = idx >> 8;
    size_t base = ((size_t)rowi * HIDN + col) >> 2;
    f32x4 a0 = ((const f32x4*)P)[base], a1 = ((const f32x4*)P)[base + 1];
    for (int s = 1; s < S; ++s) {
        size_t sb = (size_t)s * (128 * HIDN / 4) + base;
        a0 += ((const f32x4*)P)[sb];
        a1 += ((const f32x4*)P)[sb + 1];
    }
    u16x8 h, l;
#pragma unroll
    for (int j = 0; j < 8; ++j) {
        float v = (j < 4 ? a0[j] : a1[j - 4]) + bias[col + j];
        v = fmaxf(v, 0.f);
        u16 hh = f2bf(v);
        h[j] = hh;
        l[j] = f2bf(v - bf2f(hh));
    }
    size_t ob = tiled_off(rowi, col, HIDN);
    *(u16x8*)&hi[ob] = h;
    *(u16x8*)&lo[ob] = l;
}

// ---------------------------------------------------------------------------
// K3d: MLP2 split-K reduce + bias fused with mem_kv concat -> ck/cv [KVH][33][DH]
// ---------------------------------------------------------------------------
__global__ void reduce_ckcv(const float* __restrict__ Pk, const float* __restrict__ Pv,
                            const float* __restrict__ mem_kv,
                            const float* __restrict__ kb2, const float* __restrict__ vb2,
                            float* __restrict__ ck, float* __restrict__ cv, int S) {
    int idx = blockIdx.x * 256 + threadIdx.x;   // 4*33*64 = 8448
    if (idx >= KVH * 33 * DH) return;
    int d = idx & 63;
    int j = (idx >> 6) % 33;
    int h = idx / (33 * 64);
    float kvv, vvv;
    if (j == 0) {
        kvv = mem_kv[(0 * KVH + h) * DH + d];
        vvv = mem_kv[(1 * KVH + h) * DH + d];
    } else {
        size_t base = (size_t)(h * WBLK + (j - 1)) * 128 + d;
        float ak = Pk[base], av = Pv[base];
        for (int s = 1; s < S; ++s) {
            ak += Pk[(size_t)s * (128 * 128) + base];
            av += Pv[(size_t)s * (128 * 128) + base];
        }
        kvv = ak + kb2[d];
        vvv = av + vb2[d];
    }
    ck[idx] = kvv;
    cv[idx] = vvv;
}

// ---------------------------------------------------------------------------
// K5: build compress-MLP inputs -> split-bf16 TILED (K=CDIM)
// ---------------------------------------------------------------------------
__global__ void build_cmlp_in(const float* __restrict__ qkv, const float* __restrict__ k_pos,
                              const float* __restrict__ v_pos,
                              u16* __restrict__ ckhi, u16* __restrict__ cklo,
                              u16* __restrict__ cvhi, u16* __restrict__ cvlo) {
    int idx = blockIdx.x * 256 + threadIdx.x;   // 128 * 256 = 32768
    int k = (idx & 255) * 8;
    int r = idx >> 8;                           // 0..127 = h*W + w
    int p = k >> 6, d = k & 63;
    int h = r >> 5, wb = r & 31;
    int nn = wb * BSZ + p;
    const float* kq = qkv + (size_t)nn * QKVD + (HEADS + h) * DH + d;
    const float* vq = qkv + (size_t)nn * QKVD + (HEADS + KVH + h) * DH + d;
    const float* kp = k_pos + (size_t)(h * BSZ + p) * DH + d;
    const float* vp = v_pos + (size_t)(h * BSZ + p) * DH + d;
    u16x8 kh, kl, vh, vl;
#pragma unroll
    for (int j = 0; j < 8; ++j) {
        float kv = kq[j] + kp[j];
        float vv = vq[j] + vp[j];
        u16 a = f2bf(kv), b = f2bf(vv);
        kh[j] = a; kl[j] = f2bf(kv - bf2f(a));
        vh[j] = b; vl[j] = f2bf(vv - bf2f(b));
    }
    size_t ob = tiled_off(r, k, CDIM);
    *(u16x8*)&ckhi[ob] = kh; *(u16x8*)&cklo[ob] = kl;
    *(u16x8*)&cvhi[ob] = vh; *(u16x8*)&cvlo[ob] = vl;
}

// ---------------------------------------------------------------------------
// K7: interleaved rotary for q (16 heads), k (4 heads) + packed v copy (4 heads)
// ---------------------------------------------------------------------------
__global__ void rotary_kernel(const float* __restrict__ qkv,
                              float* __restrict__ qr, float* __restrict__ kr,
                              float* __restrict__ vr) {
    int idx = blockIdx.x * 256 + threadIdx.x;   // 24*1024*32 = 786432
    int i = idx & 31;
    int n = (idx >> 5) & 1023;
    int hd = idx >> 15;
    if (hd >= 24) return;
    if (hd >= HEADS + KVH) {       // packed v copy
        int h = hd - (HEADS + KVH);
        const float* src = qkv + (size_t)n * QKVD + (HEADS + KVH + h) * DH;
        float* dst = vr + ((size_t)h * NTOK + n) * DH;
        dst[2 * i] = src[2 * i];
        dst[2 * i + 1] = src[2 * i + 1];
        return;
    }
    float inv = powf(10000.f, -(float)i / 32.f);
    float fr = (float)n * inv;
    float c = cosf(fr), s = sinf(fr);
    const float* src; float* dst;
    if (hd < HEADS) { src = qkv + (size_t)n * QKVD + hd * DH;          dst = qr + ((size_t)hd * NTOK + n) * DH; }
    else { int h = hd - HEADS;
           src = qkv + (size_t)n * QKVD + (HEADS + h) * DH;            dst = kr + ((size_t)h * NTOK + n) * DH; }
    float x0 = src[2 * i], x1 = src[2 * i + 1];
    dst[2 * i]     = x0 * c - x1 * s;
    dst[2 * i + 1] = x1 * c + x0 * s;
}

// ---------------------------------------------------------------------------
// K8: compressed attention + importance + top-k. 4 tokens per 256-thr block.
// ---------------------------------------------------------------------------
__global__ __launch_bounds__(256)
void cattn_kernel(const float* __restrict__ qkv, const float* __restrict__ ck,
                  const float* __restrict__ cv, float* __restrict__ c_out,
                  int* __restrict__ sel, int* __restrict__ selmask) {
    int h = blockIdx.y;
    int tid = threadIdx.x;
    int w = tid >> 6, lane = tid & 63;
    int grp = lane >> 4, sub = lane & 15;
    int n = blockIdx.x * 4 + w;
    __shared__ float cks[33 * 68];
    __shared__ float cvs[33 * 68];
    __shared__ float sims[16 * 36];      // [w*4+g][j]

    for (int t4 = tid; t4 < 1056; t4 += 256) {
        int half = (t4 >= 528) ? 1 : 0;
        int u = t4 - half * 528;
        int j = u >> 4, d4 = (u & 15) * 4;
        const float* src = (half ? cv : ck) + (size_t)h * 33 * 64 + j * 64 + d4;
        float* dst = (half ? cvs : cks) + j * 68 + d4;
        *(float4*)dst = *(const float4*)src;
    }
    float qreg[64];
    {
        const float4* qp4 = (const float4*)(qkv + (size_t)n * QKVD + (h * GQ + grp) * DH);
#pragma unroll
        for (int c = 0; c < 16; ++c) {
            float4 v = qp4[c];
            qreg[4 * c] = v.x; qreg[4 * c + 1] = v.y; qreg[4 * c + 2] = v.z; qreg[4 * c + 3] = v.w;
        }
    }
    __syncthreads();

#pragma unroll
    for (int r = 0; r < 3; ++r) {
        int j = r * 16 + sub;
        if (j < 33) {
            float acc = 0.f;
#pragma unroll
            for (int d = 0; d < 64; ++d) acc = fmaf(qreg[d], cks[j * 68 + d], acc);
            sims[(w * 4 + grp) * 36 + j] = acc * SCALE;
        }
    }

    float ival = NEGINF;
    if (lane < 32)
        ival = 0.25f * (sims[(w * 4 + 0) * 36 + 1 + lane] + sims[(w * 4 + 1) * 36 + 1 + lane] +
                        sims[(w * 4 + 2) * 36 + 1 + lane] + sims[(w * 4 + 3) * 36 + 1 + lane]);
    float m = ival;
    for (int off = 32; off; off >>= 1) m = fmaxf(m, __shfl_xor(m, off));
    float e = (lane < 32) ? expf(ival - m) : 0.f;
    float sum = e;
    for (int off = 32; off; off >>= 1) sum += __shfl_xor(sum, off);
    float p = (lane < 32) ? e / sum : NEGINF;

    float v = p;
    int base = (h * NTOK + n) * 9;
    for (int t = 0; t < NSEL; ++t) {
        float bv = v; int bi = lane;
        for (int off = 32; off; off >>= 1) {
            float ov = __shfl_xor(bv, off);
            int   oi = __shfl_xor(bi, off);
            if (ov > bv || (ov == bv && oi < bi)) { bv = ov; bi = oi; }
        }
        if (lane == 0) { sel[base + t] = bi; selmask[base + t] = (bv > 1e-10f) ? 1 : 0; }
        if (lane == bi) v = NEGINF;
    }
    if (lane == 0) { sel[base + NSEL] = n >> 5; selmask[base + NSEL] = 1; }

#pragma unroll
    for (int g = 0; g < 4; ++g) {
        float sv = (lane < 33) ? sims[(w * 4 + g) * 36 + lane] : NEGINF;
        float mm = sv;
        for (int off = 32; off; off >>= 1) mm = fmaxf(mm, __shfl_xor(mm, off));
        float ee = (lane < 33) ? __expf(sv - mm) : 0.f;
        float ssum = ee;
        for (int off = 32; off; off >>= 1) ssum += __shfl_xor(ssum, off);
        if (lane < 33) sims[(w * 4 + g) * 36 + lane] = ee / ssum;
    }

    f32x4 o = (f32x4){0.f, 0.f, 0.f, 0.f};
#pragma unroll
    for (int j = 0; j < 33; ++j) {
        float a = sims[(w * 4 + grp) * 36 + j];
        f32x4 vv = *(const f32x4*)&cvs[j * 68 + sub * 4];
        o += a * vv;
    }
    *(f32x4*)&c_out[(((size_t)(h * GQ + grp)) * NTOK + n) * DH + sub * 4] = o;
}

// ---------------------------------------------------------------------------
// K9: fine attention v5 — NO K/V LDS staging (kr/vr are L2-resident, 2 MB).
// Score: lane (g=grp, jj=w*16+sub) reads K row direct from global (quad-bcast
// coalesced). Online softmax: wave w owns head w (v2-proven math). PV: lane
// (g=grp, d-chunk=sub) accumulates f32x4 over wave's jj-slice, V from global;
// cross-wave reduce once at end. LDS ~8 KB; 2 barriers/pair; q in LDS (no
// qreg[64] -> no spill; round-6 spill was VGPR 256 + 850 MB scratch traffic).
// ---------------------------------------------------------------------------
__global__ __launch_bounds__(256, 6)
void fattn_kernel(const float* __restrict__ qr, const float* __restrict__ kr,
                  const float* __restrict__ vr, const int* __restrict__ sel,
                  const int* __restrict__ selmask, float* __restrict__ f_out) {
    int n = blockIdx.x, h = blockIdx.y;
    int tid = threadIdx.x;
    int w = tid >> 6, lane = tid & 63;
    int grp = lane >> 4, sub = lane & 15;
    __shared__ float qsm[4 * 68];
    __shared__ float ssc[4 * 68];
    __shared__ float ps[4 * 68];
    __shared__ f32x4 red[256];
    __shared__ float alphas[4], ls[4];
    __shared__ int sel_s[9], msk_s[9];

    if (tid < 9) {
        sel_s[tid] = sel[(h * NTOK + n) * 9 + tid];
        msk_s[tid] = selmask[(h * NTOK + n) * 9 + tid];
    }
    qsm[w * 68 + lane] = qr[(((size_t)(h * GQ + w)) * NTOK + n) * DH + lane];
    __syncthreads();

    const float* krh_ = kr + (size_t)h * NTOK * DH;
    const float* vrh_ = vr + (size_t)h * NTOK * DH;

    f32x4 o4 = (f32x4){0.f, 0.f, 0.f, 0.f};
    float m_run = -3.402823466e38f, l_run = 0.f;

    for (int bp = 0; bp < 5; ++bp) {
        // ---- scores: s(head=grp, key jj=w*16+sub), K direct from global
        int jj = w * 16 + sub;
        int b9 = bp * 2 + (jj >> 5);
        float s = -3.402823466e38f;
        if (b9 < 9 && msk_s[b9]) {
            const float* krow = krh_ + (size_t)(sel_s[b9] * BSZ + (jj & 31)) * DH;
            float acc = 0.f;
#pragma unroll
            for (int c = 0; c < 16; ++c) {
                f32x4 k4 = *(const f32x4*)&krow[c * 4];
                f32x4 q4 = *(const f32x4*)&qsm[grp * 68 + c * 4];
                acc = fmaf(q4[0], k4[0], acc);
                acc = fmaf(q4[1], k4[1], acc);
                acc = fmaf(q4[2], k4[2], acc);
                acc = fmaf(q4[3], k4[3], acc);
            }
            s = acc * SCALE;
        }
        ssc[grp * 68 + jj] = s;
        __syncthreads();

        // ---- online softmax update: wave w owns head w, lane = key index
        {
            float sv = ssc[w * 68 + lane];
            float mb = sv;
            for (int off = 32; off; off >>= 1) mb = fmaxf(mb, __shfl_xor(mb, off));
            float m_new = fmaxf(m_run, mb);
            float pp = (sv > -1e37f) ? __expf(sv - m_new) : 0.f;
            float alpha = __expf(m_run - m_new);
            float psum = pp;
            for (int off = 32; off; off >>= 1) psum += __shfl_xor(psum, off);
            l_run = l_run * alpha + psum;
            m_run = m_new;
            ps[w * 68 + lane] = pp;
            if (lane == 0) alphas[w] = alpha;
        }
        __syncthreads();

        // ---- PV: o4(head=grp, d=sub*4..+3) over wave's jj slice, V from global
        o4 *= alphas[grp];
#pragma unroll
        for (int t = 0; t < 16; ++t) {
            int j2 = w * 16 + t;
            int c9 = bp * 2 + (j2 >> 5);
            if (c9 < 9) {
                float p = ps[grp * 68 + j2];
                f32x4 v4 = *(const f32x4*)&vrh_[(size_t)(sel_s[c9] * BSZ + (j2 & 31)) * DH + sub * 4];
                o4 += p * v4;
            }
        }
    }
    if (lane == 0) ls[w] = l_run;
    red[tid] = o4;
    __syncthreads();
    if (w == 0) {
        f32x4 a = red[tid] + red[64 + tid] + red[128 + tid] + red[192 + tid];
        float inv = 1.f / ls[grp];
        a *= inv;
        *(f32x4*)&f_out[(((size_t)(h * GQ + grp)) * NTOK + n) * DH + sub * 4] = a;
    }
}

// ---------------------------------------------------------------------------
// K10: gated mix -> split-bf16 TILED (K=DDIM). gates f32 [N][128] padded.
// ---------------------------------------------------------------------------
__global__ void mix_kernel(const float* __restrict__ gates, const float* __restrict__ c_out,
                           const float* __restrict__ f_out,
                           u16* __restrict__ mixhi, u16* __restrict__ mixlo) {
    int idx = blockIdx.x * 256 + threadIdx.x;   // 1024*1024/8 = 131072
    int col = (idx & 127) * 8;
    int n = idx >> 7;
    int hd = col >> 6, d = col & 63;
    float g0 = gates[(size_t)n * 128 + hd * 2];
    float g1 = gates[(size_t)n * 128 + hd * 2 + 1];
    size_t hoff = (((size_t)hd) * NTOK + n) * DH + d;
    u16x8 h, l;
#pragma unroll
    for (int j = 0; j < 8; ++j) {
        float v = g0 * c_out[hoff + j] + g1 * f_out[hoff + j];
        u16 hh = f2bf(v);
        h[j] = hh;
        l[j] = f2bf(v - bf2f(hh));
    }
    size_t ob = tiled_off(n, col, DDIM);
    *(u16x8*)&mixhi[ob] = h;
    *(u16x8*)&mixlo[ob] = l;
}

// ---------------------------------------------------------------------------
extern "C" void kernel_launch(void* const* d_in, const int* in_sizes, int n_in,
                              void* d_out, int out_size, void* d_ws, size_t ws_size,
                              hipStream_t stream) {
    const float* inp    = (const float*)d_in[0];
    const float* g_norm = (const float*)d_in[1];
    const float* w_qkv  = (const float*)d_in[2];
    const float* mem_kv = (const float*)d_in[3];
    const float* k_pos  = (const float*)d_in[4];
    const float* v_pos  = (const float*)d_in[5];
    const float* k_w1   = (const float*)d_in[6];
    const float* k_b1   = (const float*)d_in[7];
    const float* k_w2   = (const float*)d_in[8];
    const float* k_b2   = (const float*)d_in[9];
    const float* v_w1   = (const float*)d_in[10];
    const float* v_b1   = (const float*)d_in[11];
    const float* v_w2   = (const float*)d_in[12];
    const float* v_b2   = (const float*)d_in[13];
    const float* gate_w = (const float*)d_in[14];
    const float* gate_b = (const float*)d_in[15];
    const float* w_out  = (const float*)d_in[16];
    float* out = (float*)d_out;

    char* wsb = (char*)d_ws;
    size_t off = 0;
    auto alloc = [&](size_t bytes) -> void* {
        void* p = wsb + off;
        off = (off + bytes + 255) & ~(size_t)255;
        return p;
    };
    u16*   xhi    = (u16*)  alloc((size_t)NTOK * DDIM * 2);
    u16*   xlo    = (u16*)  alloc((size_t)NTOK * DDIM * 2);
    float* qkvb   = (float*)alloc((size_t)NTOK * QKVD * 4);
    u16*   wqThi  = (u16*)  alloc((size_t)QKVD * DDIM * 2);
    u16*   wqTlo  = (u16*)  alloc((size_t)QKVD * DDIM * 2);
    u16*   kw1Thi = (u16*)  alloc((size_t)HIDN * CDIM * 2);
    u16*   kw1Tlo = (u16*)  alloc((size_t)HIDN * CDIM * 2);
    u16*   vw1Thi = (u16*)  alloc((size_t)HIDN * CDIM * 2);
    u16*   vw1Tlo = (u16*)  alloc((size_t)HIDN * CDIM * 2);
    u16*   woThi  = (u16*)  alloc((size_t)DDIM * DDIM * 2);
    u16*   gwThi  = (u16*)  alloc((size_t)128 * DDIM * 2);
    u16*   gwTlo  = (u16*)  alloc((size_t)128 * DDIM * 2);
    float* gbp    = (float*)alloc(128 * 4);
    u16*   kw2Thi = (u16*)  alloc((size_t)128 * HIDN * 2);
    u16*   kw2Tlo = (u16*)  alloc((size_t)128 * HIDN * 2);
    float* kb2p   = (float*)alloc(128 * 4);
    u16*   vw2Thi = (u16*)  alloc((size_t)128 * HIDN * 2);
    u16*   vw2Tlo = (u16*)  alloc((size_t)128 * HIDN * 2);
    float* vb2p   = (float*)alloc(128 * 4);
    u16*   cinkhi = (u16*)  alloc((size_t)128 * CDIM * 2);
    u16*   cinklo = (u16*)  alloc((size_t)128 * CDIM * 2);
    u16*   cinvhi = (u16*)  alloc((size_t)128 * CDIM * 2);
    u16*   cinvlo = (u16*)  alloc((size_t)128 * CDIM * 2);
    u16*   hidkhi = (u16*)  alloc((size_t)128 * HIDN * 2);
    u16*   hidklo = (u16*)  alloc((size_t)128 * HIDN * 2);
    u16*   hidvhi = (u16*)  alloc((size_t)128 * HIDN * 2);
    u16*   hidvlo = (u16*)  alloc((size_t)128 * HIDN * 2);
    float* Pg     = (float*)alloc((size_t)8 * NTOK * 128 * 4);
    float* Pm1k   = (float*)alloc((size_t)4 * 128 * HIDN * 4);
    float* Pm1v   = (float*)alloc((size_t)4 * 128 * HIDN * 4);
    float* Pm2k   = (float*)alloc((size_t)8 * 128 * 128 * 4);
    float* Pm2v   = (float*)alloc((size_t)8 * 128 * 128 * 4);
    float* ck     = (float*)alloc((size_t)KVH * 33 * DH * 4);
    float* cv     = (float*)alloc((size_t)KVH * 33 * DH * 4);
    float* qr     = (float*)alloc((size_t)HEADS * NTOK * DH * 4);
    float* kr     = (float*)alloc((size_t)KVH * NTOK * DH * 4);
    float* vr     = (float*)alloc((size_t)KVH * NTOK * DH * 4);
    float* c_out  = (float*)alloc((size_t)HEADS * NTOK * DH * 4);
    float* f_out  = (float*)alloc((size_t)HEADS * NTOK * DH * 4);
    float* gates  = (float*)alloc((size_t)NTOK * 128 * 4);
    int*   sel    = (int*)  alloc((size_t)KVH * NTOK * 9 * 4);
    int*   selmask= (int*)  alloc((size_t)KVH * NTOK * 9 * 4);
    u16*   mixhi  = (u16*)  alloc((size_t)NTOK * DDIM * 2);
    u16*   mixlo  = (u16*)  alloc((size_t)NTOK * DDIM * 2);

    // weight prep (tiled layouts)
    transpose_split<<<dim3(QKVD / 64, DDIM / 64), 256, 0, stream>>>(w_qkv, wqThi, wqTlo, DDIM, QKVD);
    transpose_split<<<dim3(HIDN / 64, CDIM / 64), 256, 0, stream>>>(k_w1, kw1Thi, kw1Tlo, CDIM, HIDN);
    transpose_split<<<dim3(HIDN / 64, CDIM / 64), 256, 0, stream>>>(v_w1, vw1Thi, vw1Tlo, CDIM, HIDN);
    transpose_split<<<dim3(DDIM / 64, DDIM / 64), 256, 0, stream>>>(w_out, woThi, nullptr, DDIM, DDIM);
    pad_small_tiled<<<(128 * DDIM / 8) / 256, 256, 0, stream>>>(gate_w, gate_b, gwThi, gwTlo, gbp, DDIM, 32, 10);
    pad_small_tiled<<<(128 * HIDN / 8) / 256, 256, 0, stream>>>(k_w2, k_b2, kw2Thi, kw2Tlo, kb2p, HIDN, 64, 11);
    pad_small_tiled<<<(128 * HIDN / 8) / 256, 256, 0, stream>>>(v_w2, v_b2, vw2Thi, vw2Tlo, vb2p, HIDN, 64, 11);

    // 1. RMSNorm -> tiled split-bf16 x
    rmsnorm_kernel<<<NTOK / 2, 256, 0, stream>>>(inp, g_norm, xhi, xlo);
    // 2. qkv = x @ w_qkv (final f32)
    gemm_tiled<3, 0, 1><<<dim3(QKVD / 128, NTOK / 128, 1), 256, 0, stream>>>(
        xhi, xlo, wqThi, wqTlo, nullptr, qkvb,
        xhi, xlo, wqThi, wqTlo, nullptr, qkvb, NTOK, QKVD, DDIM, 1);
    // 3. gates (split-K 8 + sigmoid reduce)
    gemm_tiled<3, 0, 0><<<dim3(1, NTOK / 128, 8), 256, 0, stream>>>(
        xhi, xlo, gwThi, gwTlo, nullptr, Pg,
        xhi, xlo, gwThi, gwTlo, nullptr, Pg, NTOK, 128, DDIM, 8);
    reduce_f32<2><<<dim3(128, 1), 256, 0, stream>>>(Pg, gbp, gates, Pg, gbp, gates, 8, NTOK, 128);
    // 4. compress-MLP inputs (tiled)
    build_cmlp_in<<<128, 256, 0, stream>>>(qkvb, k_pos, v_pos, cinkhi, cinklo, cinvhi, cinvlo);
    // 5. MLP1 (split-K 4, k&v batched; relu+bias+split-tile in reduce)
    gemm_tiled<3, 0, 0><<<dim3(HIDN / 128, 1, 8), 256, 0, stream>>>(
        cinkhi, cinklo, kw1Thi, kw1Tlo, nullptr, Pm1k,
        cinvhi, cinvlo, vw1Thi, vw1Tlo, nullptr, Pm1v, 128, HIDN, CDIM, 4);
    reduce_hid<<<dim3(128, 2), 256, 0, stream>>>(Pm1k, k_b1, hidkhi, hidklo,
                                                 Pm1v, v_b1, hidvhi, hidvlo, 4);
    // 6. MLP2 (split-K 8, k&v batched) + fused reduce/bias/concat
    gemm_tiled<3, 0, 0><<<dim3(1, 1, 16), 256, 0, stream>>>(
        hidkhi, hidklo, kw2Thi, kw2Tlo, nullptr, Pm2k,
        hidvhi, hidvlo, vw2Thi, vw2Tlo, nullptr, Pm2v, 128, 128, HIDN, 8);
    reduce_ckcv<<<33, 256, 0, stream>>>(Pm2k, Pm2v, mem_kv, kb2p, vb2p, ck, cv, 8);
    // 8. rotary + packed v
    rotary_kernel<<<(24 * NTOK * 32) / 256, 256, 0, stream>>>(qkvb, qr, kr, vr);
    // 9. compressed attention + selection (4 tokens per block)
    cattn_kernel<<<dim3(NTOK / 4, KVH), 256, 0, stream>>>(qkvb, ck, cv, c_out, sel, selmask);
    // 10. fine attention (v5: global K/V, no staging, 2 barriers/pair)
    fattn_kernel<<<dim3(NTOK, KVH), 256, 0, stream>>>(qr, kr, vr, sel, selmask, f_out);
    // 11. gated mix -> tiled split-bf16
    mix_kernel<<<(NTOK * DDIM / 8) / 256, 256, 0, stream>>>(gates, c_out, f_out, mixhi, mixlo);
    // 12. output projection (bf16, final)
    gemm_tiled<1, 0, 1><<<dim3(DDIM / 128, NTOK / 128, 1), 256, 0, stream>>>(
        mixhi, mixhi, woThi, woThi, nullptr, out,
        mixhi, mixhi, woThi, woThi, nullptr, out, NTOK, DDIM, DDIM, 1);
}

// Round 8
// 393.874 us; speedup vs baseline: 2.1408x; 1.4479x over previous
//
#include <hip/hip_runtime.h>
#include <math.h>

// ---- fixed problem sizes ----
#define NTOK 1024
#define DDIM 1024
#define HEADS 16
#define KVH 4
#define DH 64
#define BSZ 32
#define NSEL 8
#define WBLK 32            // NTOK / BSZ
#define GQ 4               // HEADS / KVH
#define CDIM 2048          // BSZ*DH
#define HIDN 2048
#define QKVD 1536          // (HEADS + 2*KVH)*DH
#define SCALE 0.125f       // DH^-0.5
#define NEGINF (-__builtin_inff())

typedef unsigned short u16;
typedef u16   u16x8  __attribute__((ext_vector_type(8)));
typedef short short8 __attribute__((ext_vector_type(8)));
typedef float f32x4  __attribute__((ext_vector_type(4)));

__device__ __forceinline__ u16 f2bf(float f) {
    unsigned u = __float_as_uint(f);
    return (u16)((u + 0x7fffu + ((u >> 16) & 1u)) >> 16);
}
__device__ __forceinline__ float bf2f(u16 h) { return __uint_as_float(((unsigned)h) << 16); }

__device__ __forceinline__ void glds16(const void* g, void* l) {
    __builtin_amdgcn_global_load_lds(
        (const __attribute__((address_space(1))) unsigned int*)g,
        (__attribute__((address_space(3))) unsigned int*)l, 16, 0, 0);
}

// element offset (in u16) of the 8-element lane-slot for (row, k..k+7) in the
// MFMA-fragment-tiled layout: 16-row x 32-k tiles, 1KB each, contiguous.
__device__ __forceinline__ size_t tiled_off(int row, int k, int K) {
    return ((size_t)((row >> 4) * (K >> 5) + (k >> 5)) * 64 +
            ((row & 15) | (((k >> 3) & 3) << 4))) * 8;
}

// ---------------------------------------------------------------------------
// K1: RMSNorm -> split-bf16 x in TILED layout (K=DDIM). 2 rows per 256-thr block.
// ---------------------------------------------------------------------------
__global__ void rmsnorm_kernel(const float* __restrict__ inp, const float* __restrict__ g,
                               u16* __restrict__ xhi, u16* __restrict__ xlo) {
    int t = threadIdx.x;
    int half = t >> 7, tid = t & 127;
    int n = blockIdx.x * 2 + half;
    const float4* row = (const float4*)(inp + (size_t)n * DDIM);
    float4 v0 = row[tid * 2], v1 = row[tid * 2 + 1];
    float ss = v0.x*v0.x + v0.y*v0.y + v0.z*v0.z + v0.w*v0.w
             + v1.x*v1.x + v1.y*v1.y + v1.z*v1.z + v1.w*v1.w;
    for (int off = 32; off; off >>= 1) ss += __shfl_down(ss, off);
    __shared__ float red[4];
    if ((t & 63) == 0) red[t >> 6] = ss;
    __syncthreads();
    float tot = red[half * 2] + red[half * 2 + 1];
    float r = 1.f / sqrtf(tot * (1.f / DDIM) + 1e-6f);
    const float4* gp = (const float4*)g;
    float4 g0 = gp[tid * 2], g1 = gp[tid * 2 + 1];
    float o[8] = { v0.x*r*g0.x, v0.y*r*g0.y, v0.z*r*g0.z, v0.w*r*g0.w,
                   v1.x*r*g1.x, v1.y*r*g1.y, v1.z*r*g1.z, v1.w*r*g1.w };
    u16x8 h, l;
#pragma unroll
    for (int i = 0; i < 8; ++i) {
        u16 hh = f2bf(o[i]);
        h[i] = hh;
        l[i] = f2bf(o[i] - bf2f(hh));
    }
    size_t ob = tiled_off(n, tid * 8, DDIM);
    *(u16x8*)&xhi[ob] = h;
    *(u16x8*)&xlo[ob] = l;
}

// ---------------------------------------------------------------------------
// K2: weight transpose + split: W[K][N] f32 -> tiled Bt[N][K] bf16 hi/lo
// ---------------------------------------------------------------------------
__global__ void transpose_split(const float* __restrict__ W, u16* __restrict__ Thi,
                                u16* __restrict__ Tlo, int K, int N) {
    __shared__ float tile[64][65];
    int k0 = blockIdx.y * 64, n0 = blockIdx.x * 64;
    int t = threadIdx.x;
    int r = t >> 4, c4 = (t & 15) * 4;
#pragma unroll
    for (int p = 0; p < 4; ++p) {
        float4 v = *(const float4*)&W[(size_t)(k0 + r + p * 16) * N + n0 + c4];
        tile[r + p * 16][c4 + 0] = v.x;
        tile[r + p * 16][c4 + 1] = v.y;
        tile[r + p * 16][c4 + 2] = v.z;
        tile[r + p * 16][c4 + 3] = v.w;
    }
    __syncthreads();
    int n = t >> 2, ks = (t & 3) * 16;
#pragma unroll
    for (int c = 0; c < 2; ++c) {
        u16x8 h, l;
#pragma unroll
        for (int j = 0; j < 8; ++j) {
            float v = tile[ks + c * 8 + j][n];
            u16 hh = f2bf(v);
            h[j] = hh;
            l[j] = f2bf(v - bf2f(hh));
        }
        size_t ob = tiled_off(n0 + n, k0 + ks + c * 8, K);
        *(u16x8*)&Thi[ob] = h;
        if (Tlo) *(u16x8*)&Tlo[ob] = l;
    }
}

// ---------------------------------------------------------------------------
// K2b: pad small weights [K][Xn] (Xn<=64) -> tiled split-bf16 [128][K] + padded bias
// ---------------------------------------------------------------------------
__global__ void pad_small_tiled(const float* __restrict__ W, const float* __restrict__ b,
                                u16* __restrict__ Thi, u16* __restrict__ Tlo,
                                float* __restrict__ bias_pad, int K, int Xn, int KLOG) {
    int idx = blockIdx.x * 256 + threadIdx.x;   // 128 * K/8
    int k = (idx & ((K >> 3) - 1)) * 8;
    int n = idx >> (KLOG - 3);
    if (n >= 128) return;
    u16x8 h, l;
#pragma unroll
    for (int j = 0; j < 8; ++j) {
        float v = (n < Xn) ? W[(size_t)(k + j) * Xn + n] : 0.f;
        u16 hh = f2bf(v);
        h[j] = hh;
        l[j] = f2bf(v - bf2f(hh));
    }
    size_t ob = tiled_off(n, k, K);
    *(u16x8*)&Thi[ob] = h;
    *(u16x8*)&Tlo[ob] = l;
    if (k == 0) bias_pad[n] = (n < Xn) ? b[n] : 0.f;
}

// ---------------------------------------------------------------------------
// K3: tiled MFMA GEMM with software pipeline + optional split-K.
// ---------------------------------------------------------------------------
template<int SPLIT, int ACT, int FINAL>
__global__ __launch_bounds__(256, 1)
void gemm_tiled(const u16* __restrict__ Ahi0, const u16* __restrict__ Alo0,
                const u16* __restrict__ Bhi0, const u16* __restrict__ Blo0,
                const float* __restrict__ bias0, float* __restrict__ C0,
                const u16* __restrict__ Ahi1, const u16* __restrict__ Alo1,
                const u16* __restrict__ Bhi1, const u16* __restrict__ Blo1,
                const float* __restrict__ bias1, float* __restrict__ C1,
                int M, int N, int K, int S) {
    int batch = blockIdx.z / S;
    int s = blockIdx.z - batch * S;
    const u16* Ahi = batch ? Ahi1 : Ahi0;
    const u16* Alo = batch ? Alo1 : Alo0;
    const u16* Bhi = batch ? Bhi1 : Bhi0;
    const u16* Blo = batch ? Blo1 : Blo0;
    const float* bias = batch ? bias1 : bias0;
    float* C = batch ? C1 : C0;

    constexpr int PARTS = (SPLIT == 3) ? 2 : 1;
    __shared__ u16 smA[2 * PARTS * 8 * 512];
    __shared__ u16 smB[2 * PARTS * 8 * 512];

    int tid = threadIdx.x;
    int w = tid >> 6, L = tid & 63;
    int m15 = L & 15, q = L >> 4;
    int KT = K >> 5;
    int rowTile = blockIdx.y * 8, colTile = blockIdx.x * 8;
    int NIT = (K / S) >> 5;
    int kb0 = s * NIT;
    int aw = w & 1, bw = w >> 1;

    f32x4 acc[4][4];
#pragma unroll
    for (int i = 0; i < 4; ++i)
#pragma unroll
        for (int j = 0; j < 4; ++j) acc[i][j] = (f32x4){0.f, 0.f, 0.f, 0.f};

    auto stage = [&](int buf, int kb) {
#pragma unroll
        for (int rl = 0; rl < 2; ++rl) {
            int rb = 2 * w + rl;
            glds16(Ahi + ((size_t)(rowTile + rb) * KT + kb) * 512 + (size_t)L * 8,
                   &smA[((buf * PARTS + 0) * 8 + rb) * 512]);
            glds16(Bhi + ((size_t)(colTile + rb) * KT + kb) * 512 + (size_t)L * 8,
                   &smB[((buf * PARTS + 0) * 8 + rb) * 512]);
            if constexpr (SPLIT == 3) {
                glds16(Alo + ((size_t)(rowTile + rb) * KT + kb) * 512 + (size_t)L * 8,
                       &smA[((buf * PARTS + 1) * 8 + rb) * 512]);
                glds16(Blo + ((size_t)(colTile + rb) * KT + kb) * 512 + (size_t)L * 8,
                       &smB[((buf * PARTS + 1) * 8 + rb) * 512]);
            }
        }
    };

    stage(0, kb0);
    for (int it = 0; it < NIT; ++it) {
        __syncthreads();
        if (it + 1 < NIT) stage((it + 1) & 1, kb0 + it + 1);
        int buf = it & 1;
        short8 ah[4], bh[4];
#pragma unroll
        for (int i = 0; i < 4; ++i) {
            ah[i] = *(const short8*)&smA[((buf * PARTS + 0) * 8 + aw * 4 + i) * 512 + L * 8];
            bh[i] = *(const short8*)&smB[((buf * PARTS + 0) * 8 + bw * 4 + i) * 512 + L * 8];
        }
        if constexpr (SPLIT == 3) {
            short8 al[4], bl[4];
#pragma unroll
            for (int i = 0; i < 4; ++i) {
                al[i] = *(const short8*)&smA[((buf * PARTS + 1) * 8 + aw * 4 + i) * 512 + L * 8];
                bl[i] = *(const short8*)&smB[((buf * PARTS + 1) * 8 + bw * 4 + i) * 512 + L * 8];
            }
#pragma unroll
            for (int i = 0; i < 4; ++i)
#pragma unroll
                for (int j = 0; j < 4; ++j) {
                    acc[i][j] = __builtin_amdgcn_mfma_f32_16x16x32_bf16(ah[i], bl[j], acc[i][j], 0, 0, 0);
                    acc[i][j] = __builtin_amdgcn_mfma_f32_16x16x32_bf16(al[i], bh[j], acc[i][j], 0, 0, 0);
                    acc[i][j] = __builtin_amdgcn_mfma_f32_16x16x32_bf16(ah[i], bh[j], acc[i][j], 0, 0, 0);
                }
        } else {
#pragma unroll
            for (int i = 0; i < 4; ++i)
#pragma unroll
                for (int j = 0; j < 4; ++j)
                    acc[i][j] = __builtin_amdgcn_mfma_f32_16x16x32_bf16(ah[i], bh[j], acc[i][j], 0, 0, 0);
        }
    }

    if constexpr (FINAL == 0) C += (size_t)s * M * N;
#pragma unroll
    for (int i = 0; i < 4; ++i) {
        int row = rowTile * 16 + aw * 64 + i * 16 + q * 4;
#pragma unroll
        for (int j = 0; j < 4; ++j) {
            int col = colTile * 16 + bw * 64 + j * 16 + m15;
            float bv = (FINAL && bias) ? bias[col] : 0.f;
#pragma unroll
            for (int r = 0; r < 4; ++r) {
                float v = acc[i][j][r];
                if constexpr (FINAL) {
                    v += bv;
                    if (ACT == 1) v = fmaxf(v, 0.f);
                    if (ACT == 2) v = 1.f / (1.f + expf(-v));
                }
                C[(size_t)(row + r) * N + col] = v;
            }
        }
    }
}

// ---------------------------------------------------------------------------
// K3b: split-K reduce -> f32 [M][N] with bias/act. Dual pointer sets via blockIdx.y.
// ---------------------------------------------------------------------------
template<int ACT>
__global__ void reduce_f32(const float* __restrict__ P0, const float* __restrict__ bias0,
                           float* __restrict__ C0,
                           const float* __restrict__ P1, const float* __restrict__ bias1,
                           float* __restrict__ C1, int S, int M, int N) {
    const float* P = blockIdx.y ? P1 : P0;
    const float* bias = blockIdx.y ? bias1 : bias0;
    float* C = blockIdx.y ? C1 : C0;
    int idx = blockIdx.x * 256 + threadIdx.x;
    int mn4 = (M * N) >> 2;
    if (idx >= mn4) return;
    f32x4 a = ((const f32x4*)P)[idx];
    for (int s = 1; s < S; ++s) a += ((const f32x4*)P)[(size_t)s * mn4 + idx];
    int col = (idx % (N >> 2)) * 4;
    f32x4 o;
#pragma unroll
    for (int j = 0; j < 4; ++j) {
        float v = a[j] + (bias ? bias[col + j] : 0.f);
        if (ACT == 1) v = fmaxf(v, 0.f);
        if (ACT == 2) v = 1.f / (1.f + expf(-v));
        o[j] = v;
    }
    ((f32x4*)C)[idx] = o;
}

// ---------------------------------------------------------------------------
// K3c: split-K reduce + relu + bias -> split-bf16 TILED (MLP1 hid, M=128, N=HIDN)
// ---------------------------------------------------------------------------
__global__ void reduce_hid(const float* __restrict__ P0, const float* __restrict__ b0,
                           u16* __restrict__ hi0, u16* __restrict__ lo0,
                           const float* __restrict__ P1, const float* __restrict__ b1,
                           u16* __restrict__ hi1, u16* __restrict__ lo1, int S) {
    const float* P = blockIdx.y ? P1 : P0;
    const float* bias = blockIdx.y ? b1 : b0;
    u16* hi = blockIdx.y ? hi1 : hi0;
    u16* lo = blockIdx.y ? lo1 : lo0;
    int idx = blockIdx.x * 256 + threadIdx.x;       // 128*2048/8 = 32768
    int col = (idx & 255) * 8, rowi = idx >> 8;
    size_t base = ((size_t)rowi * HIDN + col) >> 2;
    f32x4 a0 = ((const f32x4*)P)[base], a1 = ((const f32x4*)P)[base + 1];
    for (int s = 1; s < S; ++s) {
        size_t sb = (size_t)s * (128 * HIDN / 4) + base;
        a0 += ((const f32x4*)P)[sb];
        a1 += ((const f32x4*)P)[sb + 1];
    }
    u16x8 h, l;
#pragma unroll
    for (int j = 0; j < 8; ++j) {
        float v = (j < 4 ? a0[j] : a1[j - 4]) + bias[col + j];
        v = fmaxf(v, 0.f);
        u16 hh = f2bf(v);
        h[j] = hh;
        l[j] = f2bf(v - bf2f(hh));
    }
    size_t ob = tiled_off(rowi, col, HIDN);
    *(u16x8*)&hi[ob] = h;
    *(u16x8*)&lo[ob] = l;
}

// ---------------------------------------------------------------------------
// K3d: MLP2 split-K reduce + bias fused with mem_kv concat -> ck/cv [KVH][33][DH]
// ---------------------------------------------------------------------------
__global__ void reduce_ckcv(const float* __restrict__ Pk, const float* __restrict__ Pv,
                            const float* __restrict__ mem_kv,
                            const float* __restrict__ kb2, const float* __restrict__ vb2,
                            float* __restrict__ ck, float* __restrict__ cv, int S) {
    int idx = blockIdx.x * 256 + threadIdx.x;   // 4*33*64 = 8448
    if (idx >= KVH * 33 * DH) return;
    int d = idx & 63;
    int j = (idx >> 6) % 33;
    int h = idx / (33 * 64);
    float kvv, vvv;
    if (j == 0) {
        kvv = mem_kv[(0 * KVH + h) * DH + d];
        vvv = mem_kv[(1 * KVH + h) * DH + d];
    } else {
        size_t base = (size_t)(h * WBLK + (j - 1)) * 128 + d;
        float ak = Pk[base], av = Pv[base];
        for (int s = 1; s < S; ++s) {
            ak += Pk[(size_t)s * (128 * 128) + base];
            av += Pv[(size_t)s * (128 * 128) + base];
        }
        kvv = ak + kb2[d];
        vvv = av + vb2[d];
    }
    ck[idx] = kvv;
    cv[idx] = vvv;
}

// ---------------------------------------------------------------------------
// K5: build compress-MLP inputs -> split-bf16 TILED (K=CDIM)
// ---------------------------------------------------------------------------
__global__ void build_cmlp_in(const float* __restrict__ qkv, const float* __restrict__ k_pos,
                              const float* __restrict__ v_pos,
                              u16* __restrict__ ckhi, u16* __restrict__ cklo,
                              u16* __restrict__ cvhi, u16* __restrict__ cvlo) {
    int idx = blockIdx.x * 256 + threadIdx.x;   // 128 * 256 = 32768
    int k = (idx & 255) * 8;
    int r = idx >> 8;                           // 0..127 = h*W + w
    int p = k >> 6, d = k & 63;
    int h = r >> 5, wb = r & 31;
    int nn = wb * BSZ + p;
    const float* kq = qkv + (size_t)nn * QKVD + (HEADS + h) * DH + d;
    const float* vq = qkv + (size_t)nn * QKVD + (HEADS + KVH + h) * DH + d;
    const float* kp = k_pos + (size_t)(h * BSZ + p) * DH + d;
    const float* vp = v_pos + (size_t)(h * BSZ + p) * DH + d;
    u16x8 kh, kl, vh, vl;
#pragma unroll
    for (int j = 0; j < 8; ++j) {
        float kv = kq[j] + kp[j];
        float vv = vq[j] + vp[j];
        u16 a = f2bf(kv), b = f2bf(vv);
        kh[j] = a; kl[j] = f2bf(kv - bf2f(a));
        vh[j] = b; vl[j] = f2bf(vv - bf2f(b));
    }
    size_t ob = tiled_off(r, k, CDIM);
    *(u16x8*)&ckhi[ob] = kh; *(u16x8*)&cklo[ob] = kl;
    *(u16x8*)&cvhi[ob] = vh; *(u16x8*)&cvlo[ob] = vl;
}

// ---------------------------------------------------------------------------
// K7: interleaved rotary for q (16 heads), k (4 heads) + packed v copy (4 heads)
// ---------------------------------------------------------------------------
__global__ void rotary_kernel(const float* __restrict__ qkv,
                              float* __restrict__ qr, float* __restrict__ kr,
                              float* __restrict__ vr) {
    int idx = blockIdx.x * 256 + threadIdx.x;   // 24*1024*32 = 786432
    int i = idx & 31;
    int n = (idx >> 5) & 1023;
    int hd = idx >> 15;
    if (hd >= 24) return;
    if (hd >= HEADS + KVH) {       // packed v copy
        int h = hd - (HEADS + KVH);
        const float* src = qkv + (size_t)n * QKVD + (HEADS + KVH + h) * DH;
        float* dst = vr + ((size_t)h * NTOK + n) * DH;
        dst[2 * i] = src[2 * i];
        dst[2 * i + 1] = src[2 * i + 1];
        return;
    }
    float inv = powf(10000.f, -(float)i / 32.f);
    float fr = (float)n * inv;
    float c = cosf(fr), s = sinf(fr);
    const float* src; float* dst;
    if (hd < HEADS) { src = qkv + (size_t)n * QKVD + hd * DH;          dst = qr + ((size_t)hd * NTOK + n) * DH; }
    else { int h = hd - HEADS;
           src = qkv + (size_t)n * QKVD + (HEADS + h) * DH;            dst = kr + ((size_t)h * NTOK + n) * DH; }
    float x0 = src[2 * i], x1 = src[2 * i + 1];
    dst[2 * i]     = x0 * c - x1 * s;
    dst[2 * i + 1] = x1 * c + x0 * s;
}

// ---------------------------------------------------------------------------
// K8: compressed attention + importance + top-k. 4 tokens per 256-thr block.
// ---------------------------------------------------------------------------
__global__ __launch_bounds__(256)
void cattn_kernel(const float* __restrict__ qkv, const float* __restrict__ ck,
                  const float* __restrict__ cv, float* __restrict__ c_out,
                  int* __restrict__ sel, int* __restrict__ selmask) {
    int h = blockIdx.y;
    int tid = threadIdx.x;
    int w = tid >> 6, lane = tid & 63;
    int grp = lane >> 4, sub = lane & 15;
    int n = blockIdx.x * 4 + w;
    __shared__ float cks[33 * 68];
    __shared__ float cvs[33 * 68];
    __shared__ float sims[16 * 36];      // [w*4+g][j]

    for (int t4 = tid; t4 < 1056; t4 += 256) {
        int half = (t4 >= 528) ? 1 : 0;
        int u = t4 - half * 528;
        int j = u >> 4, d4 = (u & 15) * 4;
        const float* src = (half ? cv : ck) + (size_t)h * 33 * 64 + j * 64 + d4;
        float* dst = (half ? cvs : cks) + j * 68 + d4;
        *(float4*)dst = *(const float4*)src;
    }
    float qreg[64];
    {
        const float4* qp4 = (const float4*)(qkv + (size_t)n * QKVD + (h * GQ + grp) * DH);
#pragma unroll
        for (int c = 0; c < 16; ++c) {
            float4 v = qp4[c];
            qreg[4 * c] = v.x; qreg[4 * c + 1] = v.y; qreg[4 * c + 2] = v.z; qreg[4 * c + 3] = v.w;
        }
    }
    __syncthreads();

#pragma unroll
    for (int r = 0; r < 3; ++r) {
        int j = r * 16 + sub;
        if (j < 33) {
            float acc = 0.f;
#pragma unroll
            for (int d = 0; d < 64; ++d) acc = fmaf(qreg[d], cks[j * 68 + d], acc);
            sims[(w * 4 + grp) * 36 + j] = acc * SCALE;
        }
    }

    float ival = NEGINF;
    if (lane < 32)
        ival = 0.25f * (sims[(w * 4 + 0) * 36 + 1 + lane] + sims[(w * 4 + 1) * 36 + 1 + lane] +
                        sims[(w * 4 + 2) * 36 + 1 + lane] + sims[(w * 4 + 3) * 36 + 1 + lane]);
    float m = ival;
    for (int off = 32; off; off >>= 1) m = fmaxf(m, __shfl_xor(m, off));
    float e = (lane < 32) ? expf(ival - m) : 0.f;
    float sum = e;
    for (int off = 32; off; off >>= 1) sum += __shfl_xor(sum, off);
    float p = (lane < 32) ? e / sum : NEGINF;

    float v = p;
    int base = (h * NTOK + n) * 9;
    for (int t = 0; t < NSEL; ++t) {
        float bv = v; int bi = lane;
        for (int off = 32; off; off >>= 1) {
            float ov = __shfl_xor(bv, off);
            int   oi = __shfl_xor(bi, off);
            if (ov > bv || (ov == bv && oi < bi)) { bv = ov; bi = oi; }
        }
        if (lane == 0) { sel[base + t] = bi; selmask[base + t] = (bv > 1e-10f) ? 1 : 0; }
        if (lane == bi) v = NEGINF;
    }
    if (lane == 0) { sel[base + NSEL] = n >> 5; selmask[base + NSEL] = 1; }

#pragma unroll
    for (int g = 0; g < 4; ++g) {
        float sv = (lane < 33) ? sims[(w * 4 + g) * 36 + lane] : NEGINF;
        float mm = sv;
        for (int off = 32; off; off >>= 1) mm = fmaxf(mm, __shfl_xor(mm, off));
        float ee = (lane < 33) ? __expf(sv - mm) : 0.f;
        float ssum = ee;
        for (int off = 32; off; off >>= 1) ssum += __shfl_xor(ssum, off);
        if (lane < 33) sims[(w * 4 + g) * 36 + lane] = ee / ssum;
    }

    f32x4 o = (f32x4){0.f, 0.f, 0.f, 0.f};
#pragma unroll
    for (int j = 0; j < 33; ++j) {
        float a = sims[(w * 4 + grp) * 36 + j];
        f32x4 vv = *(const f32x4*)&cvs[j * 68 + sub * 4];
        o += a * vv;
    }
    *(f32x4*)&c_out[(((size_t)(h * GQ + grp)) * NTOK + n) * DH + sub * 4] = o;
}

// ---------------------------------------------------------------------------
// K9: fine attention v6 — v2 structure (LDS-staged, proven 94us/15MB traffic)
// with a SINGLE shared K/V buffer: stage K -> score -> stage V (overwrite,
// overlapped with softmax) -> PV. LDS 37KB -> ~21KB (=> ~6 blocks/CU vs 4),
// 3 barriers/pair. Math/order identical to round-5 v2 (same absmax).
// NOTE: round-4's 4.7M "conflicts" were 2-way = free (m136); the real v2
// limiter was LDS capacity, which this fixes.
// ---------------------------------------------------------------------------
__global__ __launch_bounds__(256)
void fattn_kernel(const float* __restrict__ qr, const float* __restrict__ kr,
                  const float* __restrict__ vr, const int* __restrict__ sel,
                  const int* __restrict__ selmask, float* __restrict__ f_out) {
    int n = blockIdx.x, h = blockIdx.y;
    int tid = threadIdx.x;
    int w = tid >> 6, lane = tid & 63;
    int grp = lane >> 4, sub = lane & 15;
    __shared__ float KV[64 * 68];        // K, then overwritten with V each pair
    __shared__ float ssc[4 * 68];
    __shared__ float ps[4 * 68];
    __shared__ float alphas[4], ls[4];
    __shared__ int sel_s[9], msk_s[9];

    if (tid < 9) {
        sel_s[tid] = sel[(h * NTOK + n) * 9 + tid];
        msk_s[tid] = selmask[(h * NTOK + n) * 9 + tid];
    }
    float qreg[64];
    {
        const float4* qp4 = (const float4*)(qr + (((size_t)(h * GQ + grp)) * NTOK + n) * DH);
#pragma unroll
        for (int c = 0; c < 16; ++c) {
            float4 vv = qp4[c];
            qreg[4 * c] = vv.x; qreg[4 * c + 1] = vv.y; qreg[4 * c + 2] = vv.z; qreg[4 * c + 3] = vv.w;
        }
    }
    float o = 0.f;
    float m_run = -3.402823466e38f, l_run = 0.f;
    __syncthreads();

    const float* krh_ = kr + (size_t)h * NTOK * DH;
    const float* vrh_ = vr + (size_t)h * NTOK * DH;

    for (int bp = 0; bp < 5; ++bp) {
        int nrow = (bp < 4) ? 64 : 32;
        // ---- stage K rows into shared buffer
        for (int t4 = tid; t4 < nrow * 16; t4 += 256) {
            int row = t4 >> 4, d4 = (t4 & 15) * 4;
            int blk = sel_s[bp * 2 + (row >> 5)];
            *(float4*)&KV[row * 68 + d4] =
                *(const float4*)&krh_[(size_t)(blk * BSZ + (row & 31)) * DH + d4];
        }
        __syncthreads();                  // B1: K staged

        // ---- scores: thread -> (g=grp, jj=w*16+sub)
        {
            int jj = w * 16 + sub;
            int b = bp * 2 + (jj >> 5);
            float s = -3.402823466e38f;
            if (jj < nrow && msk_s[b]) {
                float acc = 0.f;
#pragma unroll
                for (int c = 0; c < 16; ++c) {
                    f32x4 k4 = *(const f32x4*)&KV[jj * 68 + c * 4];
                    acc = fmaf(qreg[4 * c + 0], k4[0], acc);
                    acc = fmaf(qreg[4 * c + 1], k4[1], acc);
                    acc = fmaf(qreg[4 * c + 2], k4[2], acc);
                    acc = fmaf(qreg[4 * c + 3], k4[3], acc);
                }
                s = acc * SCALE;
            }
            ssc[grp * 68 + jj] = s;
        }
        __syncthreads();                  // B2: scores done, K reads done

        // ---- stage V rows (overwrite KV) + online softmax (wave w owns head w)
        for (int t4 = tid; t4 < nrow * 16; t4 += 256) {
            int row = t4 >> 4, d4 = (t4 & 15) * 4;
            int blk = sel_s[bp * 2 + (row >> 5)];
            *(float4*)&KV[row * 68 + d4] =
                *(const float4*)&vrh_[(size_t)(blk * BSZ + (row & 31)) * DH + d4];
        }
        {
            float sv = ssc[w * 68 + lane];
            float mb = sv;
            for (int off = 32; off; off >>= 1) mb = fmaxf(mb, __shfl_xor(mb, off));
            float m_new = fmaxf(m_run, mb);
            float pp = (sv > -1e37f) ? __expf(sv - m_new) : 0.f;
            float alpha = __expf(m_run - m_new);
            float psum = pp;
            for (int off = 32; off; off >>= 1) psum += __shfl_xor(psum, off);
            l_run = l_run * alpha + psum;
            m_run = m_new;
            ps[w * 68 + lane] = pp;
            if (lane == 0) alphas[w] = alpha;
        }
        __syncthreads();                  // B3: V staged, ps/alphas ready

        // ---- PV: thread -> (g=grp, d=w*16+sub)
        {
            int d = w * 16 + sub;
            o *= alphas[grp];
#pragma unroll
            for (int j4 = 0; j4 < 16; ++j4) {
                f32x4 p4 = *(const f32x4*)&ps[grp * 68 + j4 * 4];
                o = fmaf(p4[0], KV[(j4 * 4 + 0) * 68 + d], o);
                o = fmaf(p4[1], KV[(j4 * 4 + 1) * 68 + d], o);
                o = fmaf(p4[2], KV[(j4 * 4 + 2) * 68 + d], o);
                o = fmaf(p4[3], KV[(j4 * 4 + 3) * 68 + d], o);
            }
        }
        __syncthreads();                  // B4 = B1 of next pair (KV free)
    }
    if (lane == 0) ls[w] = l_run;
    __syncthreads();
    int d = w * 16 + sub;
    f_out[(((size_t)(h * GQ + grp)) * NTOK + n) * DH + d] = o / ls[grp];
}

// ---------------------------------------------------------------------------
// K10: gated mix -> split-bf16 TILED (K=DDIM). gates f32 [N][128] padded.
// ---------------------------------------------------------------------------
__global__ void mix_kernel(const float* __restrict__ gates, const float* __restrict__ c_out,
                           const float* __restrict__ f_out,
                           u16* __restrict__ mixhi, u16* __restrict__ mixlo) {
    int idx = blockIdx.x * 256 + threadIdx.x;   // 1024*1024/8 = 131072
    int col = (idx & 127) * 8;
    int n = idx >> 7;
    int hd = col >> 6, d = col & 63;
    float g0 = gates[(size_t)n * 128 + hd * 2];
    float g1 = gates[(size_t)n * 128 + hd * 2 + 1];
    size_t hoff = (((size_t)hd) * NTOK + n) * DH + d;
    u16x8 h, l;
#pragma unroll
    for (int j = 0; j < 8; ++j) {
        float v = g0 * c_out[hoff + j] + g1 * f_out[hoff + j];
        u16 hh = f2bf(v);
        h[j] = hh;
        l[j] = f2bf(v - bf2f(hh));
    }
    size_t ob = tiled_off(n, col, DDIM);
    *(u16x8*)&mixhi[ob] = h;
    *(u16x8*)&mixlo[ob] = l;
}

// ---------------------------------------------------------------------------
extern "C" void kernel_launch(void* const* d_in, const int* in_sizes, int n_in,
                              void* d_out, int out_size, void* d_ws, size_t ws_size,
                              hipStream_t stream) {
    const float* inp    = (const float*)d_in[0];
    const float* g_norm = (const float*)d_in[1];
    const float* w_qkv  = (const float*)d_in[2];
    const float* mem_kv = (const float*)d_in[3];
    const float* k_pos  = (const float*)d_in[4];
    const float* v_pos  = (const float*)d_in[5];
    const float* k_w1   = (const float*)d_in[6];
    const float* k_b1   = (const float*)d_in[7];
    const float* k_w2   = (const float*)d_in[8];
    const float* k_b2   = (const float*)d_in[9];
    const float* v_w1   = (const float*)d_in[10];
    const float* v_b1   = (const float*)d_in[11];
    const float* v_w2   = (const float*)d_in[12];
    const float* v_b2   = (const float*)d_in[13];
    const float* gate_w = (const float*)d_in[14];
    const float* gate_b = (const float*)d_in[15];
    const float* w_out  = (const float*)d_in[16];
    float* out = (float*)d_out;

    char* wsb = (char*)d_ws;
    size_t off = 0;
    auto alloc = [&](size_t bytes) -> void* {
        void* p = wsb + off;
        off = (off + bytes + 255) & ~(size_t)255;
        return p;
    };
    u16*   xhi    = (u16*)  alloc((size_t)NTOK * DDIM * 2);
    u16*   xlo    = (u16*)  alloc((size_t)NTOK * DDIM * 2);
    float* qkvb   = (float*)alloc((size_t)NTOK * QKVD * 4);
    u16*   wqThi  = (u16*)  alloc((size_t)QKVD * DDIM * 2);
    u16*   wqTlo  = (u16*)  alloc((size_t)QKVD * DDIM * 2);
    u16*   kw1Thi = (u16*)  alloc((size_t)HIDN * CDIM * 2);
    u16*   kw1Tlo = (u16*)  alloc((size_t)HIDN * CDIM * 2);
    u16*   vw1Thi = (u16*)  alloc((size_t)HIDN * CDIM * 2);
    u16*   vw1Tlo = (u16*)  alloc((size_t)HIDN * CDIM * 2);
    u16*   woThi  = (u16*)  alloc((size_t)DDIM * DDIM * 2);
    u16*   gwThi  = (u16*)  alloc((size_t)128 * DDIM * 2);
    u16*   gwTlo  = (u16*)  alloc((size_t)128 * DDIM * 2);
    float* gbp    = (float*)alloc(128 * 4);
    u16*   kw2Thi = (u16*)  alloc((size_t)128 * HIDN * 2);
    u16*   kw2Tlo = (u16*)  alloc((size_t)128 * HIDN * 2);
    float* kb2p   = (float*)alloc(128 * 4);
    u16*   vw2Thi = (u16*)  alloc((size_t)128 * HIDN * 2);
    u16*   vw2Tlo = (u16*)  alloc((size_t)128 * HIDN * 2);
    float* vb2p   = (float*)alloc(128 * 4);
    u16*   cinkhi = (u16*)  alloc((size_t)128 * CDIM * 2);
    u16*   cinklo = (u16*)  alloc((size_t)128 * CDIM * 2);
    u16*   cinvhi = (u16*)  alloc((size_t)128 * CDIM * 2);
    u16*   cinvlo = (u16*)  alloc((size_t)128 * CDIM * 2);
    u16*   hidkhi = (u16*)  alloc((size_t)128 * HIDN * 2);
    u16*   hidklo = (u16*)  alloc((size_t)128 * HIDN * 2);
    u16*   hidvhi = (u16*)  alloc((size_t)128 * HIDN * 2);
    u16*   hidvlo = (u16*)  alloc((size_t)128 * HIDN * 2);
    float* Pg     = (float*)alloc((size_t)8 * NTOK * 128 * 4);
    float* Pm1k   = (float*)alloc((size_t)4 * 128 * HIDN * 4);
    float* Pm1v   = (float*)alloc((size_t)4 * 128 * HIDN * 4);
    float* Pm2k   = (float*)alloc((size_t)8 * 128 * 128 * 4);
    float* Pm2v   = (float*)alloc((size_t)8 * 128 * 128 * 4);
    float* ck     = (float*)alloc((size_t)KVH * 33 * DH * 4);
    float* cv     = (float*)alloc((size_t)KVH * 33 * DH * 4);
    float* qr     = (float*)alloc((size_t)HEADS * NTOK * DH * 4);
    float* kr     = (float*)alloc((size_t)KVH * NTOK * DH * 4);
    float* vr     = (float*)alloc((size_t)KVH * NTOK * DH * 4);
    float* c_out  = (float*)alloc((size_t)HEADS * NTOK * DH * 4);
    float* f_out  = (float*)alloc((size_t)HEADS * NTOK * DH * 4);
    float* gates  = (float*)alloc((size_t)NTOK * 128 * 4);
    int*   sel    = (int*)  alloc((size_t)KVH * NTOK * 9 * 4);
    int*   selmask= (int*)  alloc((size_t)KVH * NTOK * 9 * 4);
    u16*   mixhi  = (u16*)  alloc((size_t)NTOK * DDIM * 2);
    u16*   mixlo  = (u16*)  alloc((size_t)NTOK * DDIM * 2);

    // weight prep (tiled layouts)
    transpose_split<<<dim3(QKVD / 64, DDIM / 64), 256, 0, stream>>>(w_qkv, wqThi, wqTlo, DDIM, QKVD);
    transpose_split<<<dim3(HIDN / 64, CDIM / 64), 256, 0, stream>>>(k_w1, kw1Thi, kw1Tlo, CDIM, HIDN);
    transpose_split<<<dim3(HIDN / 64, CDIM / 64), 256, 0, stream>>>(v_w1, vw1Thi, vw1Tlo, CDIM, HIDN);
    transpose_split<<<dim3(DDIM / 64, DDIM / 64), 256, 0, stream>>>(w_out, woThi, nullptr, DDIM, DDIM);
    pad_small_tiled<<<(128 * DDIM / 8) / 256, 256, 0, stream>>>(gate_w, gate_b, gwThi, gwTlo, gbp, DDIM, 32, 10);
    pad_small_tiled<<<(128 * HIDN / 8) / 256, 256, 0, stream>>>(k_w2, k_b2, kw2Thi, kw2Tlo, kb2p, HIDN, 64, 11);
    pad_small_tiled<<<(128 * HIDN / 8) / 256, 256, 0, stream>>>(v_w2, v_b2, vw2Thi, vw2Tlo, vb2p, HIDN, 64, 11);

    // 1. RMSNorm -> tiled split-bf16 x
    rmsnorm_kernel<<<NTOK / 2, 256, 0, stream>>>(inp, g_norm, xhi, xlo);
    // 2. qkv = x @ w_qkv (final f32)
    gemm_tiled<3, 0, 1><<<dim3(QKVD / 128, NTOK / 128, 1), 256, 0, stream>>>(
        xhi, xlo, wqThi, wqTlo, nullptr, qkvb,
        xhi, xlo, wqThi, wqTlo, nullptr, qkvb, NTOK, QKVD, DDIM, 1);
    // 3. gates (split-K 8 + sigmoid reduce)
    gemm_tiled<3, 0, 0><<<dim3(1, NTOK / 128, 8), 256, 0, stream>>>(
        xhi, xlo, gwThi, gwTlo, nullptr, Pg,
        xhi, xlo, gwThi, gwTlo, nullptr, Pg, NTOK, 128, DDIM, 8);
    reduce_f32<2><<<dim3(128, 1), 256, 0, stream>>>(Pg, gbp, gates, Pg, gbp, gates, 8, NTOK, 128);
    // 4. compress-MLP inputs (tiled)
    build_cmlp_in<<<128, 256, 0, stream>>>(qkvb, k_pos, v_pos, cinkhi, cinklo, cinvhi, cinvlo);
    // 5. MLP1 (split-K 4, k&v batched; relu+bias+split-tile in reduce)
    gemm_tiled<3, 0, 0><<<dim3(HIDN / 128, 1, 8), 256, 0, stream>>>(
        cinkhi, cinklo, kw1Thi, kw1Tlo, nullptr, Pm1k,
        cinvhi, cinvlo, vw1Thi, vw1Tlo, nullptr, Pm1v, 128, HIDN, CDIM, 4);
    reduce_hid<<<dim3(128, 2), 256, 0, stream>>>(Pm1k, k_b1, hidkhi, hidklo,
                                                 Pm1v, v_b1, hidvhi, hidvlo, 4);
    // 6. MLP2 (split-K 8, k&v batched) + fused reduce/bias/concat
    gemm_tiled<3, 0, 0><<<dim3(1, 1, 16), 256, 0, stream>>>(
        hidkhi, hidklo, kw2Thi, kw2Tlo, nullptr, Pm2k,
        hidvhi, hidvlo, vw2Thi, vw2Tlo, nullptr, Pm2v, 128, 128, HIDN, 8);
    reduce_ckcv<<<33, 256, 0, stream>>>(Pm2k, Pm2v, mem_kv, kb2p, vb2p, ck, cv, 8);
    // 8. rotary + packed v
    rotary_kernel<<<(24 * NTOK * 32) / 256, 256, 0, stream>>>(qkvb, qr, kr, vr);
    // 9. compressed attention + selection (4 tokens per block)
    cattn_kernel<<<dim3(NTOK / 4, KVH), 256, 0, stream>>>(qkvb, ck, cv, c_out, sel, selmask);
    // 10. fine attention (v6: shared K/V buffer, 3 barriers/pair, ~21KB LDS)
    fattn_kernel<<<dim3(NTOK, KVH), 256, 0, stream>>>(qr, kr, vr, sel, selmask, f_out);
    // 11. gated mix -> tiled split-bf16
    mix_kernel<<<(NTOK * DDIM / 8) / 256, 256, 0, stream>>>(gates, c_out, f_out, mixhi, mixlo);
    // 12. output projection (bf16, final)
    gemm_tiled<1, 0, 1><<<dim3(DDIM / 128, NTOK / 128, 1), 256, 0, stream>>>(
        mixhi, mixhi, woThi, woThi, nullptr, out,
        mixhi, mixhi, woThi, woThi, nullptr, out, NTOK, DDIM, DDIM, 1);
}

// Round 9
// 370.261 us; speedup vs baseline: 2.2773x; 1.0638x over previous
//
#include <hip/hip_runtime.h>
#include <math.h>

// ---- fixed problem sizes ----
#define NTOK 1024
#define DDIM 1024
#define HEADS 16
#define KVH 4
#define DH 64
#define BSZ 32
#define NSEL 8
#define WBLK 32            // NTOK / BSZ
#define GQ 4               // HEADS / KVH
#define CDIM 2048          // BSZ*DH
#define HIDN 2048
#define QKVD 1536          // (HEADS + 2*KVH)*DH
#define SCALE 0.125f       // DH^-0.5
#define NEGINF (-__builtin_inff())

typedef unsigned short u16;
typedef u16   u16x8  __attribute__((ext_vector_type(8)));
typedef short short8 __attribute__((ext_vector_type(8)));
typedef float f32x4  __attribute__((ext_vector_type(4)));

__device__ __forceinline__ u16 f2bf(float f) {
    unsigned u = __float_as_uint(f);
    return (u16)((u + 0x7fffu + ((u >> 16) & 1u)) >> 16);
}
__device__ __forceinline__ float bf2f(u16 h) { return __uint_as_float(((unsigned)h) << 16); }

__device__ __forceinline__ void glds16(const void* g, void* l) {
    __builtin_amdgcn_global_load_lds(
        (const __attribute__((address_space(1))) unsigned int*)g,
        (__attribute__((address_space(3))) unsigned int*)l, 16, 0, 0);
}

// element offset (in u16) of the 8-element lane-slot for (row, k..k+7) in the
// MFMA-fragment-tiled layout: 16-row x 32-k tiles, 1KB each, contiguous.
__device__ __forceinline__ size_t tiled_off(int row, int k, int K) {
    return ((size_t)((row >> 4) * (K >> 5) + (k >> 5)) * 64 +
            ((row & 15) | (((k >> 3) & 3) << 4))) * 8;
}

// ---------------------------------------------------------------------------
// K1: RMSNorm -> split-bf16 x in TILED layout (K=DDIM). 2 rows per 256-thr block.
// ---------------------------------------------------------------------------
__global__ void rmsnorm_kernel(const float* __restrict__ inp, const float* __restrict__ g,
                               u16* __restrict__ xhi, u16* __restrict__ xlo) {
    int t = threadIdx.x;
    int half = t >> 7, tid = t & 127;
    int n = blockIdx.x * 2 + half;
    const float4* row = (const float4*)(inp + (size_t)n * DDIM);
    float4 v0 = row[tid * 2], v1 = row[tid * 2 + 1];
    float ss = v0.x*v0.x + v0.y*v0.y + v0.z*v0.z + v0.w*v0.w
             + v1.x*v1.x + v1.y*v1.y + v1.z*v1.z + v1.w*v1.w;
    for (int off = 32; off; off >>= 1) ss += __shfl_down(ss, off);
    __shared__ float red[4];
    if ((t & 63) == 0) red[t >> 6] = ss;
    __syncthreads();
    float tot = red[half * 2] + red[half * 2 + 1];
    float r = 1.f / sqrtf(tot * (1.f / DDIM) + 1e-6f);
    const float4* gp = (const float4*)g;
    float4 g0 = gp[tid * 2], g1 = gp[tid * 2 + 1];
    float o[8] = { v0.x*r*g0.x, v0.y*r*g0.y, v0.z*r*g0.z, v0.w*r*g0.w,
                   v1.x*r*g1.x, v1.y*r*g1.y, v1.z*r*g1.z, v1.w*r*g1.w };
    u16x8 h, l;
#pragma unroll
    for (int i = 0; i < 8; ++i) {
        u16 hh = f2bf(o[i]);
        h[i] = hh;
        l[i] = f2bf(o[i] - bf2f(hh));
    }
    size_t ob = tiled_off(n, tid * 8, DDIM);
    *(u16x8*)&xhi[ob] = h;
    *(u16x8*)&xlo[ob] = l;
}

// ---------------------------------------------------------------------------
// K2: weight transpose + split: W[K][N] f32 -> tiled Bt[N][K] bf16 hi/lo
// ---------------------------------------------------------------------------
__global__ void transpose_split(const float* __restrict__ W, u16* __restrict__ Thi,
                                u16* __restrict__ Tlo, int K, int N) {
    __shared__ float tile[64][65];
    int k0 = blockIdx.y * 64, n0 = blockIdx.x * 64;
    int t = threadIdx.x;
    int r = t >> 4, c4 = (t & 15) * 4;
#pragma unroll
    for (int p = 0; p < 4; ++p) {
        float4 v = *(const float4*)&W[(size_t)(k0 + r + p * 16) * N + n0 + c4];
        tile[r + p * 16][c4 + 0] = v.x;
        tile[r + p * 16][c4 + 1] = v.y;
        tile[r + p * 16][c4 + 2] = v.z;
        tile[r + p * 16][c4 + 3] = v.w;
    }
    __syncthreads();
    int n = t >> 2, ks = (t & 3) * 16;
#pragma unroll
    for (int c = 0; c < 2; ++c) {
        u16x8 h, l;
#pragma unroll
        for (int j = 0; j < 8; ++j) {
            float v = tile[ks + c * 8 + j][n];
            u16 hh = f2bf(v);
            h[j] = hh;
            l[j] = f2bf(v - bf2f(hh));
        }
        size_t ob = tiled_off(n0 + n, k0 + ks + c * 8, K);
        *(u16x8*)&Thi[ob] = h;
        if (Tlo) *(u16x8*)&Tlo[ob] = l;
    }
}

// ---------------------------------------------------------------------------
// K2b: pad small weights [K][Xn] (Xn<=64) -> tiled split-bf16 [128][K] + padded bias
// ---------------------------------------------------------------------------
__global__ void pad_small_tiled(const float* __restrict__ W, const float* __restrict__ b,
                                u16* __restrict__ Thi, u16* __restrict__ Tlo,
                                float* __restrict__ bias_pad, int K, int Xn, int KLOG) {
    int idx = blockIdx.x * 256 + threadIdx.x;   // 128 * K/8
    int k = (idx & ((K >> 3) - 1)) * 8;
    int n = idx >> (KLOG - 3);
    if (n >= 128) return;
    u16x8 h, l;
#pragma unroll
    for (int j = 0; j < 8; ++j) {
        float v = (n < Xn) ? W[(size_t)(k + j) * Xn + n] : 0.f;
        u16 hh = f2bf(v);
        h[j] = hh;
        l[j] = f2bf(v - bf2f(hh));
    }
    size_t ob = tiled_off(n, k, K);
    *(u16x8*)&Thi[ob] = h;
    *(u16x8*)&Tlo[ob] = l;
    if (k == 0) bias_pad[n] = (n < Xn) ? b[n] : 0.f;
}

// ---------------------------------------------------------------------------
// K3: tiled MFMA GEMM with software pipeline + optional split-K.
// ---------------------------------------------------------------------------
template<int SPLIT, int ACT, int FINAL>
__global__ __launch_bounds__(256, 1)
void gemm_tiled(const u16* __restrict__ Ahi0, const u16* __restrict__ Alo0,
                const u16* __restrict__ Bhi0, const u16* __restrict__ Blo0,
                const float* __restrict__ bias0, float* __restrict__ C0,
                const u16* __restrict__ Ahi1, const u16* __restrict__ Alo1,
                const u16* __restrict__ Bhi1, const u16* __restrict__ Blo1,
                const float* __restrict__ bias1, float* __restrict__ C1,
                int M, int N, int K, int S) {
    int batch = blockIdx.z / S;
    int s = blockIdx.z - batch * S;
    const u16* Ahi = batch ? Ahi1 : Ahi0;
    const u16* Alo = batch ? Alo1 : Alo0;
    const u16* Bhi = batch ? Bhi1 : Bhi0;
    const u16* Blo = batch ? Blo1 : Blo0;
    const float* bias = batch ? bias1 : bias0;
    float* C = batch ? C1 : C0;

    constexpr int PARTS = (SPLIT == 3) ? 2 : 1;
    __shared__ u16 smA[2 * PARTS * 8 * 512];
    __shared__ u16 smB[2 * PARTS * 8 * 512];

    int tid = threadIdx.x;
    int w = tid >> 6, L = tid & 63;
    int m15 = L & 15, q = L >> 4;
    int KT = K >> 5;
    int rowTile = blockIdx.y * 8, colTile = blockIdx.x * 8;
    int NIT = (K / S) >> 5;
    int kb0 = s * NIT;
    int aw = w & 1, bw = w >> 1;

    f32x4 acc[4][4];
#pragma unroll
    for (int i = 0; i < 4; ++i)
#pragma unroll
        for (int j = 0; j < 4; ++j) acc[i][j] = (f32x4){0.f, 0.f, 0.f, 0.f};

    auto stage = [&](int buf, int kb) {
#pragma unroll
        for (int rl = 0; rl < 2; ++rl) {
            int rb = 2 * w + rl;
            glds16(Ahi + ((size_t)(rowTile + rb) * KT + kb) * 512 + (size_t)L * 8,
                   &smA[((buf * PARTS + 0) * 8 + rb) * 512]);
            glds16(Bhi + ((size_t)(colTile + rb) * KT + kb) * 512 + (size_t)L * 8,
                   &smB[((buf * PARTS + 0) * 8 + rb) * 512]);
            if constexpr (SPLIT == 3) {
                glds16(Alo + ((size_t)(rowTile + rb) * KT + kb) * 512 + (size_t)L * 8,
                       &smA[((buf * PARTS + 1) * 8 + rb) * 512]);
                glds16(Blo + ((size_t)(colTile + rb) * KT + kb) * 512 + (size_t)L * 8,
                       &smB[((buf * PARTS + 1) * 8 + rb) * 512]);
            }
        }
    };

    stage(0, kb0);
    for (int it = 0; it < NIT; ++it) {
        __syncthreads();
        if (it + 1 < NIT) stage((it + 1) & 1, kb0 + it + 1);
        int buf = it & 1;
        short8 ah[4], bh[4];
#pragma unroll
        for (int i = 0; i < 4; ++i) {
            ah[i] = *(const short8*)&smA[((buf * PARTS + 0) * 8 + aw * 4 + i) * 512 + L * 8];
            bh[i] = *(const short8*)&smB[((buf * PARTS + 0) * 8 + bw * 4 + i) * 512 + L * 8];
        }
        if constexpr (SPLIT == 3) {
            short8 al[4], bl[4];
#pragma unroll
            for (int i = 0; i < 4; ++i) {
                al[i] = *(const short8*)&smA[((buf * PARTS + 1) * 8 + aw * 4 + i) * 512 + L * 8];
                bl[i] = *(const short8*)&smB[((buf * PARTS + 1) * 8 + bw * 4 + i) * 512 + L * 8];
            }
#pragma unroll
            for (int i = 0; i < 4; ++i)
#pragma unroll
                for (int j = 0; j < 4; ++j) {
                    acc[i][j] = __builtin_amdgcn_mfma_f32_16x16x32_bf16(ah[i], bl[j], acc[i][j], 0, 0, 0);
                    acc[i][j] = __builtin_amdgcn_mfma_f32_16x16x32_bf16(al[i], bh[j], acc[i][j], 0, 0, 0);
                    acc[i][j] = __builtin_amdgcn_mfma_f32_16x16x32_bf16(ah[i], bh[j], acc[i][j], 0, 0, 0);
                }
        } else {
#pragma unroll
            for (int i = 0; i < 4; ++i)
#pragma unroll
                for (int j = 0; j < 4; ++j)
                    acc[i][j] = __builtin_amdgcn_mfma_f32_16x16x32_bf16(ah[i], bh[j], acc[i][j], 0, 0, 0);
        }
    }

    if constexpr (FINAL == 0) C += (size_t)s * M * N;
#pragma unroll
    for (int i = 0; i < 4; ++i) {
        int row = rowTile * 16 + aw * 64 + i * 16 + q * 4;
#pragma unroll
        for (int j = 0; j < 4; ++j) {
            int col = colTile * 16 + bw * 64 + j * 16 + m15;
            float bv = (FINAL && bias) ? bias[col] : 0.f;
#pragma unroll
            for (int r = 0; r < 4; ++r) {
                float v = acc[i][j][r];
                if constexpr (FINAL) {
                    v += bv;
                    if (ACT == 1) v = fmaxf(v, 0.f);
                    if (ACT == 2) v = 1.f / (1.f + expf(-v));
                }
                C[(size_t)(row + r) * N + col] = v;
            }
        }
    }
}

// ---------------------------------------------------------------------------
// K3b: split-K reduce -> f32 [M][N] with bias/act. Dual pointer sets via blockIdx.y.
// ---------------------------------------------------------------------------
template<int ACT>
__global__ void reduce_f32(const float* __restrict__ P0, const float* __restrict__ bias0,
                           float* __restrict__ C0,
                           const float* __restrict__ P1, const float* __restrict__ bias1,
                           float* __restrict__ C1, int S, int M, int N) {
    const float* P = blockIdx.y ? P1 : P0;
    const float* bias = blockIdx.y ? bias1 : bias0;
    float* C = blockIdx.y ? C1 : C0;
    int idx = blockIdx.x * 256 + threadIdx.x;
    int mn4 = (M * N) >> 2;
    if (idx >= mn4) return;
    f32x4 a = ((const f32x4*)P)[idx];
    for (int s = 1; s < S; ++s) a += ((const f32x4*)P)[(size_t)s * mn4 + idx];
    int col = (idx % (N >> 2)) * 4;
    f32x4 o;
#pragma unroll
    for (int j = 0; j < 4; ++j) {
        float v = a[j] + (bias ? bias[col + j] : 0.f);
        if (ACT == 1) v = fmaxf(v, 0.f);
        if (ACT == 2) v = 1.f / (1.f + expf(-v));
        o[j] = v;
    }
    ((f32x4*)C)[idx] = o;
}

// ---------------------------------------------------------------------------
// K3c: split-K reduce + relu + bias -> split-bf16 TILED (MLP1 hid, M=128, N=HIDN)
// ---------------------------------------------------------------------------
__global__ void reduce_hid(const float* __restrict__ P0, const float* __restrict__ b0,
                           u16* __restrict__ hi0, u16* __restrict__ lo0,
                           const float* __restrict__ P1, const float* __restrict__ b1,
                           u16* __restrict__ hi1, u16* __restrict__ lo1, int S) {
    const float* P = blockIdx.y ? P1 : P0;
    const float* bias = blockIdx.y ? b1 : b0;
    u16* hi = blockIdx.y ? hi1 : hi0;
    u16* lo = blockIdx.y ? lo1 : lo0;
    int idx = blockIdx.x * 256 + threadIdx.x;       // 128*2048/8 = 32768
    int col = (idx & 255) * 8, rowi = idx >> 8;
    size_t base = ((size_t)rowi * HIDN + col) >> 2;
    f32x4 a0 = ((const f32x4*)P)[base], a1 = ((const f32x4*)P)[base + 1];
    for (int s = 1; s < S; ++s) {
        size_t sb = (size_t)s * (128 * HIDN / 4) + base;
        a0 += ((const f32x4*)P)[sb];
        a1 += ((const f32x4*)P)[sb + 1];
    }
    u16x8 h, l;
#pragma unroll
    for (int j = 0; j < 8; ++j) {
        float v = (j < 4 ? a0[j] : a1[j - 4]) + bias[col + j];
        v = fmaxf(v, 0.f);
        u16 hh = f2bf(v);
        h[j] = hh;
        l[j] = f2bf(v - bf2f(hh));
    }
    size_t ob = tiled_off(rowi, col, HIDN);
    *(u16x8*)&hi[ob] = h;
    *(u16x8*)&lo[ob] = l;
}

// ---------------------------------------------------------------------------
// K3d: MLP2 split-K reduce + bias fused with mem_kv concat -> ck/cv [KVH][33][DH]
// ---------------------------------------------------------------------------
__global__ void reduce_ckcv(const float* __restrict__ Pk, const float* __restrict__ Pv,
                            const float* __restrict__ mem_kv,
                            const float* __restrict__ kb2, const float* __restrict__ vb2,
                            float* __restrict__ ck, float* __restrict__ cv, int S) {
    int idx = blockIdx.x * 256 + threadIdx.x;   // 4*33*64 = 8448
    if (idx >= KVH * 33 * DH) return;
    int d = idx & 63;
    int j = (idx >> 6) % 33;
    int h = idx / (33 * 64);
    float kvv, vvv;
    if (j == 0) {
        kvv = mem_kv[(0 * KVH + h) * DH + d];
        vvv = mem_kv[(1 * KVH + h) * DH + d];
    } else {
        size_t base = (size_t)(h * WBLK + (j - 1)) * 128 + d;
        float ak = Pk[base], av = Pv[base];
        for (int s = 1; s < S; ++s) {
            ak += Pk[(size_t)s * (128 * 128) + base];
            av += Pv[(size_t)s * (128 * 128) + base];
        }
        kvv = ak + kb2[d];
        vvv = av + vb2[d];
    }
    ck[idx] = kvv;
    cv[idx] = vvv;
}

// ---------------------------------------------------------------------------
// K5: build compress-MLP inputs -> split-bf16 TILED (K=CDIM)
// ---------------------------------------------------------------------------
__global__ void build_cmlp_in(const float* __restrict__ qkv, const float* __restrict__ k_pos,
                              const float* __restrict__ v_pos,
                              u16* __restrict__ ckhi, u16* __restrict__ cklo,
                              u16* __restrict__ cvhi, u16* __restrict__ cvlo) {
    int idx = blockIdx.x * 256 + threadIdx.x;   // 128 * 256 = 32768
    int k = (idx & 255) * 8;
    int r = idx >> 8;                           // 0..127 = h*W + w
    int p = k >> 6, d = k & 63;
    int h = r >> 5, wb = r & 31;
    int nn = wb * BSZ + p;
    const float* kq = qkv + (size_t)nn * QKVD + (HEADS + h) * DH + d;
    const float* vq = qkv + (size_t)nn * QKVD + (HEADS + KVH + h) * DH + d;
    const float* kp = k_pos + (size_t)(h * BSZ + p) * DH + d;
    const float* vp = v_pos + (size_t)(h * BSZ + p) * DH + d;
    u16x8 kh, kl, vh, vl;
#pragma unroll
    for (int j = 0; j < 8; ++j) {
        float kv = kq[j] + kp[j];
        float vv = vq[j] + vp[j];
        u16 a = f2bf(kv), b = f2bf(vv);
        kh[j] = a; kl[j] = f2bf(kv - bf2f(a));
        vh[j] = b; vl[j] = f2bf(vv - bf2f(b));
    }
    size_t ob = tiled_off(r, k, CDIM);
    *(u16x8*)&ckhi[ob] = kh; *(u16x8*)&cklo[ob] = kl;
    *(u16x8*)&cvhi[ob] = vh; *(u16x8*)&cvlo[ob] = vl;
}

// ---------------------------------------------------------------------------
// K7: interleaved rotary for q (16 heads), k (4 heads) + packed v copy (4 heads)
// ---------------------------------------------------------------------------
__global__ void rotary_kernel(const float* __restrict__ qkv,
                              float* __restrict__ qr, float* __restrict__ kr,
                              float* __restrict__ vr) {
    int idx = blockIdx.x * 256 + threadIdx.x;   // 24*1024*32 = 786432
    int i = idx & 31;
    int n = (idx >> 5) & 1023;
    int hd = idx >> 15;
    if (hd >= 24) return;
    if (hd >= HEADS + KVH) {       // packed v copy
        int h = hd - (HEADS + KVH);
        const float* src = qkv + (size_t)n * QKVD + (HEADS + KVH + h) * DH;
        float* dst = vr + ((size_t)h * NTOK + n) * DH;
        dst[2 * i] = src[2 * i];
        dst[2 * i + 1] = src[2 * i + 1];
        return;
    }
    float inv = powf(10000.f, -(float)i / 32.f);
    float fr = (float)n * inv;
    float c = cosf(fr), s = sinf(fr);
    const float* src; float* dst;
    if (hd < HEADS) { src = qkv + (size_t)n * QKVD + hd * DH;          dst = qr + ((size_t)hd * NTOK + n) * DH; }
    else { int h = hd - HEADS;
           src = qkv + (size_t)n * QKVD + (HEADS + h) * DH;            dst = kr + ((size_t)h * NTOK + n) * DH; }
    float x0 = src[2 * i], x1 = src[2 * i + 1];
    dst[2 * i]     = x0 * c - x1 * s;
    dst[2 * i + 1] = x1 * c + x0 * s;
}

// ---------------------------------------------------------------------------
// K8: compressed attention + importance + top-k. 4 tokens per 256-thr block.
// ---------------------------------------------------------------------------
__global__ __launch_bounds__(256)
void cattn_kernel(const float* __restrict__ qkv, const float* __restrict__ ck,
                  const float* __restrict__ cv, float* __restrict__ c_out,
                  int* __restrict__ sel, int* __restrict__ selmask) {
    int h = blockIdx.y;
    int tid = threadIdx.x;
    int w = tid >> 6, lane = tid & 63;
    int grp = lane >> 4, sub = lane & 15;
    int n = blockIdx.x * 4 + w;
    __shared__ float cks[33 * 68];
    __shared__ float cvs[33 * 68];
    __shared__ float sims[16 * 36];      // [w*4+g][j]

    for (int t4 = tid; t4 < 1056; t4 += 256) {
        int half = (t4 >= 528) ? 1 : 0;
        int u = t4 - half * 528;
        int j = u >> 4, d4 = (u & 15) * 4;
        const float* src = (half ? cv : ck) + (size_t)h * 33 * 64 + j * 64 + d4;
        float* dst = (half ? cvs : cks) + j * 68 + d4;
        *(float4*)dst = *(const float4*)src;
    }
    float qreg[64];
    {
        const float4* qp4 = (const float4*)(qkv + (size_t)n * QKVD + (h * GQ + grp) * DH);
#pragma unroll
        for (int c = 0; c < 16; ++c) {
            float4 v = qp4[c];
            qreg[4 * c] = v.x; qreg[4 * c + 1] = v.y; qreg[4 * c + 2] = v.z; qreg[4 * c + 3] = v.w;
        }
    }
    __syncthreads();

#pragma unroll
    for (int r = 0; r < 3; ++r) {
        int j = r * 16 + sub;
        if (j < 33) {
            float acc = 0.f;
#pragma unroll
            for (int d = 0; d < 64; ++d) acc = fmaf(qreg[d], cks[j * 68 + d], acc);
            sims[(w * 4 + grp) * 36 + j] = acc * SCALE;
        }
    }

    float ival = NEGINF;
    if (lane < 32)
        ival = 0.25f * (sims[(w * 4 + 0) * 36 + 1 + lane] + sims[(w * 4 + 1) * 36 + 1 + lane] +
                        sims[(w * 4 + 2) * 36 + 1 + lane] + sims[(w * 4 + 3) * 36 + 1 + lane]);
    float m = ival;
    for (int off = 32; off; off >>= 1) m = fmaxf(m, __shfl_xor(m, off));
    float e = (lane < 32) ? expf(ival - m) : 0.f;
    float sum = e;
    for (int off = 32; off; off >>= 1) sum += __shfl_xor(sum, off);
    float p = (lane < 32) ? e / sum : NEGINF;

    float v = p;
    int base = (h * NTOK + n) * 9;
    for (int t = 0; t < NSEL; ++t) {
        float bv = v; int bi = lane;
        for (int off = 32; off; off >>= 1) {
            float ov = __shfl_xor(bv, off);
            int   oi = __shfl_xor(bi, off);
            if (ov > bv || (ov == bv && oi < bi)) { bv = ov; bi = oi; }
        }
        if (lane == 0) { sel[base + t] = bi; selmask[base + t] = (bv > 1e-10f) ? 1 : 0; }
        if (lane == bi) v = NEGINF;
    }
    if (lane == 0) { sel[base + NSEL] = n >> 5; selmask[base + NSEL] = 1; }

#pragma unroll
    for (int g = 0; g < 4; ++g) {
        float sv = (lane < 33) ? sims[(w * 4 + g) * 36 + lane] : NEGINF;
        float mm = sv;
        for (int off = 32; off; off >>= 1) mm = fmaxf(mm, __shfl_xor(mm, off));
        float ee = (lane < 33) ? __expf(sv - mm) : 0.f;
        float ssum = ee;
        for (int off = 32; off; off >>= 1) ssum += __shfl_xor(ssum, off);
        if (lane < 33) sims[(w * 4 + g) * 36 + lane] = ee / ssum;
    }

    f32x4 o = (f32x4){0.f, 0.f, 0.f, 0.f};
#pragma unroll
    for (int j = 0; j < 33; ++j) {
        float a = sims[(w * 4 + grp) * 36 + j];
        f32x4 vv = *(const f32x4*)&cvs[j * 68 + sub * 4];
        o += a * vv;
    }
    *(f32x4*)&c_out[(((size_t)(h * GQ + grp)) * NTOK + n) * DH + sub * 4] = o;
}

// ---------------------------------------------------------------------------
// K9: fine attention v7 — v6 structure with q in LDS (not 64 VGPRs).
// Round-8 post-mortem: VGPR=68 > 64 halves waves/SIMD (m69 cliff) -> 30% occ.
// q in qsm[4][68] read as b128 broadcasts (16 lanes same addr = free).
// __launch_bounds__(256,8) pins allocator <=64 VGPR (natural ~40, v5-measured).
// Math/order identical to v6/v2 (same absmax).
// ---------------------------------------------------------------------------
__global__ __launch_bounds__(256, 8)
void fattn_kernel(const float* __restrict__ qr, const float* __restrict__ kr,
                  const float* __restrict__ vr, const int* __restrict__ sel,
                  const int* __restrict__ selmask, float* __restrict__ f_out) {
    int n = blockIdx.x, h = blockIdx.y;
    int tid = threadIdx.x;
    int w = tid >> 6, lane = tid & 63;
    int grp = lane >> 4, sub = lane & 15;
    __shared__ float qsm[4 * 68];
    __shared__ float KV[64 * 68];        // K, then overwritten with V each pair
    __shared__ float ssc[4 * 68];
    __shared__ float ps[4 * 68];
    __shared__ float alphas[4], ls[4];
    __shared__ int sel_s[9], msk_s[9];

    if (tid < 9) {
        sel_s[tid] = sel[(h * NTOK + n) * 9 + tid];
        msk_s[tid] = selmask[(h * NTOK + n) * 9 + tid];
    }
    // q -> LDS: wave w loads head w's 64 elements
    qsm[w * 68 + lane] = qr[(((size_t)(h * GQ + w)) * NTOK + n) * DH + lane];
    float o = 0.f;
    float m_run = -3.402823466e38f, l_run = 0.f;
    __syncthreads();

    const float* krh_ = kr + (size_t)h * NTOK * DH;
    const float* vrh_ = vr + (size_t)h * NTOK * DH;

    for (int bp = 0; bp < 5; ++bp) {
        int nrow = (bp < 4) ? 64 : 32;
        // ---- stage K rows into shared buffer
        for (int t4 = tid; t4 < nrow * 16; t4 += 256) {
            int row = t4 >> 4, d4 = (t4 & 15) * 4;
            int blk = sel_s[bp * 2 + (row >> 5)];
            *(float4*)&KV[row * 68 + d4] =
                *(const float4*)&krh_[(size_t)(blk * BSZ + (row & 31)) * DH + d4];
        }
        __syncthreads();                  // B1: K staged

        // ---- scores: thread -> (g=grp, jj=w*16+sub); q read from LDS (bcast)
        {
            int jj = w * 16 + sub;
            int b = bp * 2 + (jj >> 5);
            float s = -3.402823466e38f;
            if (jj < nrow && msk_s[b]) {
                float acc = 0.f;
#pragma unroll
                for (int c = 0; c < 16; ++c) {
                    f32x4 k4 = *(const f32x4*)&KV[jj * 68 + c * 4];
                    f32x4 q4 = *(const f32x4*)&qsm[grp * 68 + c * 4];
                    acc = fmaf(q4[0], k4[0], acc);
                    acc = fmaf(q4[1], k4[1], acc);
                    acc = fmaf(q4[2], k4[2], acc);
                    acc = fmaf(q4[3], k4[3], acc);
                }
                s = acc * SCALE;
            }
            ssc[grp * 68 + jj] = s;
        }
        __syncthreads();                  // B2: scores done, K reads done

        // ---- stage V rows (overwrite KV) + online softmax (wave w owns head w)
        for (int t4 = tid; t4 < nrow * 16; t4 += 256) {
            int row = t4 >> 4, d4 = (t4 & 15) * 4;
            int blk = sel_s[bp * 2 + (row >> 5)];
            *(float4*)&KV[row * 68 + d4] =
                *(const float4*)&vrh_[(size_t)(blk * BSZ + (row & 31)) * DH + d4];
        }
        {
            float sv = ssc[w * 68 + lane];
            float mb = sv;
            for (int off = 32; off; off >>= 1) mb = fmaxf(mb, __shfl_xor(mb, off));
            float m_new = fmaxf(m_run, mb);
            float pp = (sv > -1e37f) ? __expf(sv - m_new) : 0.f;
            float alpha = __expf(m_run - m_new);
            float psum = pp;
            for (int off = 32; off; off >>= 1) psum += __shfl_xor(psum, off);
            l_run = l_run * alpha + psum;
            m_run = m_new;
            ps[w * 68 + lane] = pp;
            if (lane == 0) alphas[w] = alpha;
        }
        __syncthreads();                  // B3: V staged, ps/alphas ready

        // ---- PV: thread -> (g=grp, d=w*16+sub)
        {
            int d = w * 16 + sub;
            o *= alphas[grp];
#pragma unroll
            for (int j4 = 0; j4 < 16; ++j4) {
                f32x4 p4 = *(const f32x4*)&ps[grp * 68 + j4 * 4];
                o = fmaf(p4[0], KV[(j4 * 4 + 0) * 68 + d], o);
                o = fmaf(p4[1], KV[(j4 * 4 + 1) * 68 + d], o);
                o = fmaf(p4[2], KV[(j4 * 4 + 2) * 68 + d], o);
                o = fmaf(p4[3], KV[(j4 * 4 + 3) * 68 + d], o);
            }
        }
        __syncthreads();                  // B4 = B1 of next pair (KV free)
    }
    if (lane == 0) ls[w] = l_run;
    __syncthreads();
    int d = w * 16 + sub;
    f_out[(((size_t)(h * GQ + grp)) * NTOK + n) * DH + d] = o / ls[grp];
}

// ---------------------------------------------------------------------------
// K10: gated mix -> split-bf16 TILED (K=DDIM). gates f32 [N][128] padded.
// ---------------------------------------------------------------------------
__global__ void mix_kernel(const float* __restrict__ gates, const float* __restrict__ c_out,
                           const float* __restrict__ f_out,
                           u16* __restrict__ mixhi, u16* __restrict__ mixlo) {
    int idx = blockIdx.x * 256 + threadIdx.x;   // 1024*1024/8 = 131072
    int col = (idx & 127) * 8;
    int n = idx >> 7;
    int hd = col >> 6, d = col & 63;
    float g0 = gates[(size_t)n * 128 + hd * 2];
    float g1 = gates[(size_t)n * 128 + hd * 2 + 1];
    size_t hoff = (((size_t)hd) * NTOK + n) * DH + d;
    u16x8 h, l;
#pragma unroll
    for (int j = 0; j < 8; ++j) {
        float v = g0 * c_out[hoff + j] + g1 * f_out[hoff + j];
        u16 hh = f2bf(v);
        h[j] = hh;
        l[j] = f2bf(v - bf2f(hh));
    }
    size_t ob = tiled_off(n, col, DDIM);
    *(u16x8*)&mixhi[ob] = h;
    *(u16x8*)&mixlo[ob] = l;
}

// ---------------------------------------------------------------------------
extern "C" void kernel_launch(void* const* d_in, const int* in_sizes, int n_in,
                              void* d_out, int out_size, void* d_ws, size_t ws_size,
                              hipStream_t stream) {
    const float* inp    = (const float*)d_in[0];
    const float* g_norm = (const float*)d_in[1];
    const float* w_qkv  = (const float*)d_in[2];
    const float* mem_kv = (const float*)d_in[3];
    const float* k_pos  = (const float*)d_in[4];
    const float* v_pos  = (const float*)d_in[5];
    const float* k_w1   = (const float*)d_in[6];
    const float* k_b1   = (const float*)d_in[7];
    const float* k_w2   = (const float*)d_in[8];
    const float* k_b2   = (const float*)d_in[9];
    const float* v_w1   = (const float*)d_in[10];
    const float* v_b1   = (const float*)d_in[11];
    const float* v_w2   = (const float*)d_in[12];
    const float* v_b2   = (const float*)d_in[13];
    const float* gate_w = (const float*)d_in[14];
    const float* gate_b = (const float*)d_in[15];
    const float* w_out  = (const float*)d_in[16];
    float* out = (float*)d_out;

    char* wsb = (char*)d_ws;
    size_t off = 0;
    auto alloc = [&](size_t bytes) -> void* {
        void* p = wsb + off;
        off = (off + bytes + 255) & ~(size_t)255;
        return p;
    };
    u16*   xhi    = (u16*)  alloc((size_t)NTOK * DDIM * 2);
    u16*   xlo    = (u16*)  alloc((size_t)NTOK * DDIM * 2);
    float* qkvb   = (float*)alloc((size_t)NTOK * QKVD * 4);
    u16*   wqThi  = (u16*)  alloc((size_t)QKVD * DDIM * 2);
    u16*   wqTlo  = (u16*)  alloc((size_t)QKVD * DDIM * 2);
    u16*   kw1Thi = (u16*)  alloc((size_t)HIDN * CDIM * 2);
    u16*   kw1Tlo = (u16*)  alloc((size_t)HIDN * CDIM * 2);
    u16*   vw1Thi = (u16*)  alloc((size_t)HIDN * CDIM * 2);
    u16*   vw1Tlo = (u16*)  alloc((size_t)HIDN * CDIM * 2);
    u16*   woThi  = (u16*)  alloc((size_t)DDIM * DDIM * 2);
    u16*   gwThi  = (u16*)  alloc((size_t)128 * DDIM * 2);
    u16*   gwTlo  = (u16*)  alloc((size_t)128 * DDIM * 2);
    float* gbp    = (float*)alloc(128 * 4);
    u16*   kw2Thi = (u16*)  alloc((size_t)128 * HIDN * 2);
    u16*   kw2Tlo = (u16*)  alloc((size_t)128 * HIDN * 2);
    float* kb2p   = (float*)alloc(128 * 4);
    u16*   vw2Thi = (u16*)  alloc((size_t)128 * HIDN * 2);
    u16*   vw2Tlo = (u16*)  alloc((size_t)128 * HIDN * 2);
    float* vb2p   = (float*)alloc(128 * 4);
    u16*   cinkhi = (u16*)  alloc((size_t)128 * CDIM * 2);
    u16*   cinklo = (u16*)  alloc((size_t)128 * CDIM * 2);
    u16*   cinvhi = (u16*)  alloc((size_t)128 * CDIM * 2);
    u16*   cinvlo = (u16*)  alloc((size_t)128 * CDIM * 2);
    u16*   hidkhi = (u16*)  alloc((size_t)128 * HIDN * 2);
    u16*   hidklo = (u16*)  alloc((size_t)128 * HIDN * 2);
    u16*   hidvhi = (u16*)  alloc((size_t)128 * HIDN * 2);
    u16*   hidvlo = (u16*)  alloc((size_t)128 * HIDN * 2);
    float* Pg     = (float*)alloc((size_t)8 * NTOK * 128 * 4);
    float* Pm1k   = (float*)alloc((size_t)4 * 128 * HIDN * 4);
    float* Pm1v   = (float*)alloc((size_t)4 * 128 * HIDN * 4);
    float* Pm2k   = (float*)alloc((size_t)8 * 128 * 128 * 4);
    float* Pm2v   = (float*)alloc((size_t)8 * 128 * 128 * 4);
    float* ck     = (float*)alloc((size_t)KVH * 33 * DH * 4);
    float* cv     = (float*)alloc((size_t)KVH * 33 * DH * 4);
    float* qr     = (float*)alloc((size_t)HEADS * NTOK * DH * 4);
    float* kr     = (float*)alloc((size_t)KVH * NTOK * DH * 4);
    float* vr     = (float*)alloc((size_t)KVH * NTOK * DH * 4);
    float* c_out  = (float*)alloc((size_t)HEADS * NTOK * DH * 4);
    float* f_out  = (float*)alloc((size_t)HEADS * NTOK * DH * 4);
    float* gates  = (float*)alloc((size_t)NTOK * 128 * 4);
    int*   sel    = (int*)  alloc((size_t)KVH * NTOK * 9 * 4);
    int*   selmask= (int*)  alloc((size_t)KVH * NTOK * 9 * 4);
    u16*   mixhi  = (u16*)  alloc((size_t)NTOK * DDIM * 2);
    u16*   mixlo  = (u16*)  alloc((size_t)NTOK * DDIM * 2);

    // weight prep (tiled layouts)
    transpose_split<<<dim3(QKVD / 64, DDIM / 64), 256, 0, stream>>>(w_qkv, wqThi, wqTlo, DDIM, QKVD);
    transpose_split<<<dim3(HIDN / 64, CDIM / 64), 256, 0, stream>>>(k_w1, kw1Thi, kw1Tlo, CDIM, HIDN);
    transpose_split<<<dim3(HIDN / 64, CDIM / 64), 256, 0, stream>>>(v_w1, vw1Thi, vw1Tlo, CDIM, HIDN);
    transpose_split<<<dim3(DDIM / 64, DDIM / 64), 256, 0, stream>>>(w_out, woThi, nullptr, DDIM, DDIM);
    pad_small_tiled<<<(128 * DDIM / 8) / 256, 256, 0, stream>>>(gate_w, gate_b, gwThi, gwTlo, gbp, DDIM, 32, 10);
    pad_small_tiled<<<(128 * HIDN / 8) / 256, 256, 0, stream>>>(k_w2, k_b2, kw2Thi, kw2Tlo, kb2p, HIDN, 64, 11);
    pad_small_tiled<<<(128 * HIDN / 8) / 256, 256, 0, stream>>>(v_w2, v_b2, vw2Thi, vw2Tlo, vb2p, HIDN, 64, 11);

    // 1. RMSNorm -> tiled split-bf16 x
    rmsnorm_kernel<<<NTOK / 2, 256, 0, stream>>>(inp, g_norm, xhi, xlo);
    // 2. qkv = x @ w_qkv (final f32)
    gemm_tiled<3, 0, 1><<<dim3(QKVD / 128, NTOK / 128, 1), 256, 0, stream>>>(
        xhi, xlo, wqThi, wqTlo, nullptr, qkvb,
        xhi, xlo, wqThi, wqTlo, nullptr, qkvb, NTOK, QKVD, DDIM, 1);
    // 3. gates (split-K 8 + sigmoid reduce)
    gemm_tiled<3, 0, 0><<<dim3(1, NTOK / 128, 8), 256, 0, stream>>>(
        xhi, xlo, gwThi, gwTlo, nullptr, Pg,
        xhi, xlo, gwThi, gwTlo, nullptr, Pg, NTOK, 128, DDIM, 8);
    reduce_f32<2><<<dim3(128, 1), 256, 0, stream>>>(Pg, gbp, gates, Pg, gbp, gates, 8, NTOK, 128);
    // 4. compress-MLP inputs (tiled)
    build_cmlp_in<<<128, 256, 0, stream>>>(qkvb, k_pos, v_pos, cinkhi, cinklo, cinvhi, cinvlo);
    // 5. MLP1 (split-K 4, k&v batched; relu+bias+split-tile in reduce)
    gemm_tiled<3, 0, 0><<<dim3(HIDN / 128, 1, 8), 256, 0, stream>>>(
        cinkhi, cinklo, kw1Thi, kw1Tlo, nullptr, Pm1k,
        cinvhi, cinvlo, vw1Thi, vw1Tlo, nullptr, Pm1v, 128, HIDN, CDIM, 4);
    reduce_hid<<<dim3(128, 2), 256, 0, stream>>>(Pm1k, k_b1, hidkhi, hidklo,
                                                 Pm1v, v_b1, hidvhi, hidvlo, 4);
    // 6. MLP2 (split-K 8, k&v batched) + fused reduce/bias/concat
    gemm_tiled<3, 0, 0><<<dim3(1, 1, 16), 256, 0, stream>>>(
        hidkhi, hidklo, kw2Thi, kw2Tlo, nullptr, Pm2k,
        hidvhi, hidvlo, vw2Thi, vw2Tlo, nullptr, Pm2v, 128, 128, HIDN, 8);
    reduce_ckcv<<<33, 256, 0, stream>>>(Pm2k, Pm2v, mem_kv, kb2p, vb2p, ck, cv, 8);
    // 8. rotary + packed v
    rotary_kernel<<<(24 * NTOK * 32) / 256, 256, 0, stream>>>(qkvb, qr, kr, vr);
    // 9. compressed attention + selection (4 tokens per block)
    cattn_kernel<<<dim3(NTOK / 4, KVH), 256, 0, stream>>>(qkvb, ck, cv, c_out, sel, selmask);
    // 10. fine attention (v7: q in LDS, VGPR<=64 -> full occupancy)
    fattn_kernel<<<dim3(NTOK, KVH), 256, 0, stream>>>(qr, kr, vr, sel, selmask, f_out);
    // 11. gated mix -> tiled split-bf16
    mix_kernel<<<(NTOK * DDIM / 8) / 256, 256, 0, stream>>>(gates, c_out, f_out, mixhi, mixlo);
    // 12. output projection (bf16, final)
    gemm_tiled<1, 0, 1><<<dim3(DDIM / 128, NTOK / 128, 1), 256, 0, stream>>>(
        mixhi, mixhi, woThi, woThi, nullptr, out,
        mixhi, mixhi, woThi, woThi, nullptr, out, NTOK, DDIM, DDIM, 1);
}